// Round 8
// baseline (237.834 us; speedup 1.0000x reference)
//
#include <hip/hip_runtime.h>
#include <hip/hip_bf16.h>

#define L_SEQ 512
#define D_EMB 256
#define NH 8
#define HD 32
#define LL (L_SEQ * L_SEQ)   // 262144

typedef __attribute__((ext_vector_type(8))) short short8;
typedef __attribute__((ext_vector_type(4))) float f32x4;
typedef unsigned short ushort;

__device__ __forceinline__ float bf2f(ushort u) {
    unsigned int x = ((unsigned int)u) << 16;
    float f;
    __builtin_memcpy(&f, &x, 4);
    return f;
}
__device__ __forceinline__ ushort f2bf(float x) {   // RNE (host-quality), prep only
    __hip_bfloat16 h = __float2bfloat16(x);
    ushort u;
    __builtin_memcpy(&u, &h, 2);
    return u;
}
__device__ __forceinline__ unsigned int fbits(float x) {
    unsigned int u;
    __builtin_memcpy(&u, &x, 4);
    return u;
}
__device__ __forceinline__ float asf(unsigned int u) {
    float f;
    __builtin_memcpy(&f, &u, 4);
    return f;
}
// pack bf16(a) | bf16(b)<<16, nearest-ties-away rounding, 3 VALU ops
__device__ __forceinline__ unsigned int pack_bf16rnd(float a, float b) {
    return __builtin_amdgcn_perm(fbits(b) + 0x8000u, fbits(a) + 0x8000u, 0x07060302u);
}
// hi16(x) | hi16(y)<<16  (one v_perm)
__device__ __forceinline__ unsigned int packhi(unsigned int y, unsigned int x) {
    return __builtin_amdgcn_perm(y, x, 0x07060302u);
}
// hi/lo split of two floats: .x = packed hi pair, .y = packed lo pair
__device__ __forceinline__ uint2 cvt_hilo2(float v0, float v1) {
    unsigned int hi = pack_bf16rnd(v0, v1);
    float h0 = asf(hi << 16);
    float h1 = asf(hi & 0xffff0000u);
    unsigned int lo = pack_bf16rnd(v0 - h0, v1 - h1);
    uint2 r; r.x = hi; r.y = lo;
    return r;
}

// ---------------------------------------------------------------------------
// prep (merged): block 0 builds the edge-kernel tables; blocks 1..64 do the
// projection-weight transpose+hi/lo-split.
// W1G row permutation: tile t, A-row m -> physical d = (m>>2)*64+t*4+(m&3)
// so stage-A's per-lane outputs (d = q*64+t*4+r) are LDS-contiguous.
// ---------------------------------------------------------------------------
__global__ __launch_bounds__(256) void prep_kernel(
    const float* __restrict__ We1, const float* __restrict__ be1,
    const float* __restrict__ g,   const float* __restrict__ bta,
    const float* __restrict__ We2, const float* __restrict__ be2,
    const float* __restrict__ Wq, const float* __restrict__ Wk,
    const float* __restrict__ Wv, const float* __restrict__ Wp,
    ushort* __restrict__ W1G, ushort* __restrict__ B2G, float* __restrict__ tail,
    ushort* __restrict__ WThi, ushort* __restrict__ WTlo)
{
    int t = threadIdx.x;  // 0..255
    if (blockIdx.x != 0) {
        int bx = blockIdx.x - 1;
        int w = bx >> 4, ny = bx & 15;
        const float* W = (w == 0) ? Wq : (w == 1) ? Wk : (w == 2) ? Wv : Wp;
        ushort* dh = WThi + (size_t)w * 65536;
        ushort* dl = WTlo + (size_t)w * 65536;
        int n = ny * 16 + (t >> 4);
        int k0 = (t & 15) * 16;
        ushort hbuf[16], lbuf[16];
#pragma unroll
        for (int kk = 0; kk < 16; ++kk) {
            float v = W[(size_t)(k0 + kk) * 256 + n];
            unsigned int hb = fbits(v) + 0x8000u;
            ushort hi = (ushort)(hb >> 16);
            float res = v - bf2f(hi);
            hbuf[kk] = hi;
            lbuf[kk] = (ushort)((fbits(res) + 0x8000u) >> 16);
        }
        *(short8*)(dh + (size_t)n * 256 + k0)     = *(short8*)&hbuf[0];
        *(short8*)(dh + (size_t)n * 256 + k0 + 8) = *(short8*)&hbuf[8];
        *(short8*)(dl + (size_t)n * 256 + k0)     = *(short8*)&lbuf[0];
        *(short8*)(dl + (size_t)n * 256 + k0 + 8) = *(short8*)&lbuf[8];
        return;
    }

    __shared__ float red[16][256];
    float gd = g[t], bd = bta[t];
#pragma unroll
    for (int h = 0; h < 8; ++h) {
        float w2 = We2[t * 8 + h];
        red[h][t] = gd * w2;
        red[8 + h][t] = bd * w2;
    }
    __syncthreads();
    for (int off = 128; off > 0; off >>= 1) {
        if (t < off) {
#pragma unroll
            for (int row = 0; row < 16; ++row) red[row][t] += red[row][t + off];
        }
        __syncthreads();
    }
    if (t < 8) {
        tail[t] = red[t][0];
        tail[8 + t] = red[8 + t][0] + be2[t];
    }
    if (t >= 16 && t < 32) tail[t] = 0.f;

    for (int idx = t; idx < 8192; idx += 256) {
        int j = idx & 7, lane = (idx >> 3) & 63, tile = idx >> 9;
        int m = lane & 15, q = lane >> 4;
        int k = q * 8 + j;
        int d = (m >> 2) * 64 + tile * 4 + (m & 3);   // permuted
        float v = 0.f;
        bool lo = false;
        if (k < 5)        v = We1[k * 256 + d];
        else if (k < 10)  { v = We1[(k - 5) * 256 + d]; lo = true; }
        else if (k < 15)  v = We1[(k - 10) * 256 + d];
        else if (k == 15) v = be1[d];
        else if (k == 16) { v = be1[d]; lo = true; }
        ushort hi = f2bf(v);
        W1G[idx] = lo ? f2bf(v - bf2f(hi)) : hi;
    }
    for (int idx = t; idx < 4096; idx += 256) {
        int j = idx & 7, lane = (idx >> 3) & 63, kc = idx >> 9;
        int n = lane & 15, q = lane >> 4;
        int d = kc * 32 + q * 8 + j;
        ushort out;
        if (n < 8)       out = f2bf(g[d] * We2[d * 8 + n]);
        else if (n == 8) out = 0x3F80;   // 1.0 bf16
        else             out = 0;
        B2G[idx] = out;
    }
}

// ---------------------------------------------------------------------------
// gemm_mfma: C[2048,256] = A @ W + bias (fp32-accurate via bf16 hi/lo).
// If Ct != null, write the (per b,h) transposed layout instead (K -> Kt).
// ---------------------------------------------------------------------------
__global__ __launch_bounds__(256) void gemm_mfma(
    const float* __restrict__ A0, const ushort* __restrict__ H0,
    const ushort* __restrict__ L0, const float* __restrict__ b0,
    float* __restrict__ C0, float* __restrict__ T0,
    const float* __restrict__ A1, const ushort* __restrict__ H1,
    const ushort* __restrict__ L1, const float* __restrict__ b1,
    float* __restrict__ C1, float* __restrict__ T1,
    const float* __restrict__ A2, const ushort* __restrict__ H2,
    const ushort* __restrict__ L2, const float* __restrict__ b2,
    float* __restrict__ C2, float* __restrict__ T2)
{
    const float* A; const ushort* BH; const ushort* BL;
    const float* bias; float* C; float* Ct;
    if (blockIdx.z == 0)      { A = A0; BH = H0; BL = L0; bias = b0; C = C0; Ct = T0; }
    else if (blockIdx.z == 1) { A = A1; BH = H1; BL = L1; bias = b1; C = C1; Ct = T1; }
    else                      { A = A2; BH = H2; BL = L2; bias = b2; C = C2; Ct = T2; }

    __shared__ ushort Ahi[64][40];
    __shared__ ushort Alo[64][40];

    int tid = threadIdx.x;
    int wv = tid >> 6, lane = tid & 63;
    int m = lane & 15, quad = lane >> 4;
    int bm = blockIdx.x * 64, bn = blockIdx.y * 64;

    int sm = tid >> 2, sg = (tid & 3) * 8;
    const float* Arow = A + (size_t)(bm + sm) * 256 + sg;

    int nrow = bn + wv * 16 + m;
    const ushort* bhp = BH + (size_t)nrow * 256 + quad * 8;
    const ushort* blp = BL + (size_t)nrow * 256 + quad * 8;

    f32x4 acc[4];
#pragma unroll
    for (int mt = 0; mt < 4; ++mt) acc[mt] = (f32x4){0.f, 0.f, 0.f, 0.f};

    for (int k0 = 0; k0 < 256; k0 += 32) {
        float4 a0 = *(const float4*)(Arow + k0);
        float4 a1 = *(const float4*)(Arow + k0 + 4);
        uint2 c0 = cvt_hilo2(a0.x, a0.y);
        uint2 c1 = cvt_hilo2(a0.z, a0.w);
        uint2 c2 = cvt_hilo2(a1.x, a1.y);
        uint2 c3 = cvt_hilo2(a1.z, a1.w);
        if (k0) __syncthreads();
        uint4 hq; hq.x = c0.x; hq.y = c1.x; hq.z = c2.x; hq.w = c3.x;
        uint4 lq; lq.x = c0.y; lq.y = c1.y; lq.z = c2.y; lq.w = c3.y;
        *(uint4*)&Ahi[sm][sg] = hq;
        *(uint4*)&Alo[sm][sg] = lq;
        __syncthreads();

        short8 bhi = *(const short8*)(bhp + k0);
        short8 blo = *(const short8*)(blp + k0);
#pragma unroll
        for (int mt = 0; mt < 4; ++mt) {
            short8 ahi = *(const short8*)&Ahi[mt * 16 + m][quad * 8];
            short8 alo = *(const short8*)&Alo[mt * 16 + m][quad * 8];
            acc[mt] = __builtin_amdgcn_mfma_f32_16x16x32_bf16(ahi, blo, acc[mt], 0, 0, 0);
            acc[mt] = __builtin_amdgcn_mfma_f32_16x16x32_bf16(alo, bhi, acc[mt], 0, 0, 0);
            acc[mt] = __builtin_amdgcn_mfma_f32_16x16x32_bf16(ahi, bhi, acc[mt], 0, 0, 0);
        }
    }

    float bn_bias = bias[nrow];
    if (Ct) {
        int bb = bm >> 9, l0 = bm & 511;
        float* outp = Ct + ((size_t)(bb * 256 + nrow)) * 512 + l0 + quad * 4;
#pragma unroll
        for (int mt = 0; mt < 4; ++mt) {
            float4 o;
            o.x = acc[mt][0] + bn_bias; o.y = acc[mt][1] + bn_bias;
            o.z = acc[mt][2] + bn_bias; o.w = acc[mt][3] + bn_bias;
            *(float4*)(outp + mt * 16) = o;
        }
    } else {
#pragma unroll
        for (int mt = 0; mt < 4; ++mt) {
#pragma unroll
            for (int r = 0; r < 4; ++r) {
                C[(size_t)(bm + mt * 16 + quad * 4 + r) * 256 + nrow] = acc[mt][r] + bn_bias;
            }
        }
    }
}

// ---------------------------------------------------------------------------
// stage A helper for the edge kernel: ef8 build + 16 MFMA + pack + b128 writes.
// ---------------------------------------------------------------------------
__device__ __forceinline__ void edge_stage_a(
    const short8* w1f, float4 evA, float evB, int q, int n, char* dst)
{
    unsigned int hb[5], la[5];
    hb[0] = fbits(evA.x); hb[1] = fbits(evA.y); hb[2] = fbits(evA.z);
    hb[3] = fbits(evA.w); hb[4] = fbits(evB);
    {
        float e0 = evA.x - asf(hb[0] & 0xffff0000u);
        float e1 = evA.y - asf(hb[1] & 0xffff0000u);
        float e2 = evA.z - asf(hb[2] & 0xffff0000u);
        float e3 = evA.w - asf(hb[3] & 0xffff0000u);
        float e4 = evB   - asf(hb[4] & 0xffff0000u);
        la[0] = fbits(e0) + 0x8000u;
        la[1] = fbits(e1) + 0x8000u;
        la[2] = fbits(e2) + 0x8000u;
        la[3] = fbits(e3) + 0x8000u;
        la[4] = fbits(e4) + 0x8000u;
    }
    unsigned int A0v = packhi(hb[1], hb[0]);
    unsigned int A1v = packhi(hb[3], hb[2]);
    unsigned int A2v = packhi(hb[0], hb[4]);
    unsigned int A3v = packhi(hb[2], hb[1]);
    unsigned int B0v = packhi(hb[4], hb[3]);
    unsigned int B1v = packhi(la[1], la[0]);
    unsigned int B2v = packhi(la[3], la[2]);
    unsigned int B3v = packhi(0x3F800000u, la[4]);
    uint4 efd;
    bool isq0 = (q == 0), isq1 = (q == 1), isq2 = (q == 2);
    efd.x = isq0 ? A0v : isq1 ? B0v : isq2 ? 0x3F80u : 0u;
    efd.y = isq0 ? A1v : isq1 ? B1v : 0u;
    efd.z = isq0 ? A2v : isq1 ? B2v : 0u;
    efd.w = isq0 ? A3v : isq1 ? B3v : 0u;
    short8 ef8;
    __builtin_memcpy(&ef8, &efd, 16);

    unsigned int pk0 = 0, pk1 = 0;
#pragma unroll
    for (int t = 0; t < 16; ++t) {
        f32x4 z = {0.f, 0.f, 0.f, 0.f};
        f32x4 d1 = __builtin_amdgcn_mfma_f32_16x16x32_bf16(w1f[t], ef8, z, 0, 0, 0);
        float x0 = fmaxf(d1[0], 0.f);
        float x1 = fmaxf(d1[1], 0.f);
        float x2 = fmaxf(d1[2], 0.f);
        float x3 = fmaxf(d1[3], 0.f);
        unsigned int pa = pack_bf16rnd(x0, x1);
        unsigned int pb = pack_bf16rnd(x2, x3);
        if (t & 1) {
            uint4 wq; wq.x = pk0; wq.y = pk1; wq.z = pa; wq.w = pb;
            *(uint4*)(dst + n * 528 + q * 128 + (t - 1) * 8) = wq;
        } else {
            pk0 = pa; pk1 = pb;
        }
    }
}

// ---------------------------------------------------------------------------
// edge_bias_mfma v4: iteration-level software pipeline.
//  - X double-buffered per wave: stage A of iter+1 (-> bufB) issues alongside
//    stage B of iter (<- bufA): two independent MFMA streams per wave.
//  - stage-B accumulate chains split even/odd kc (dep depth 8 -> 4).
//  - EF prefetch distance 2.
// Math bit-identical to v3.
// ---------------------------------------------------------------------------
__global__ __launch_bounds__(256) void edge_bias_mfma(
    const float* __restrict__ EF, const ushort* __restrict__ W1G,
    const ushort* __restrict__ B2G, const float* __restrict__ tail,
    ushort* __restrict__ E2)
{
    __shared__ __align__(16) char xt[2 * 4 * 16 * 528];  // 67584 B, dbuf per wave
    int tid = threadIdx.x;
    int wv = tid >> 6, lane = tid & 63;
    int q = lane >> 4, n = lane & 15;
    char* xb0 = xt + wv * (16 * 528);
    char* xb1 = xt + 33792 + wv * (16 * 528);

    int bi = blockIdx.x;            // b*512 + i
    int b = bi >> 9, i = bi & 511;
    size_t rowbase = (size_t)bi * 512;

    short8 w1f[16];
#pragma unroll
    for (int t = 0; t < 16; ++t)
        w1f[t] = *(const short8*)(W1G + (t * 64 + lane) * 8);
    short8 b2f[8];
#pragma unroll
    for (int kc = 0; kc < 8; ++kc)
        b2f[kc] = *(const short8*)(B2G + (kc * 64 + lane) * 8);

    float shv = tail[n];
    float bbv = tail[8 + n];
    const float inv256 = 1.0f / 256.0f;

    const float* efbase = EF + rowbase * 5;
    int pairoff = wv * 16 + n;

    // iter 0 EF -> stage A(0) into buf0
    float4 e0A = *(const float4*)(efbase + (size_t)pairoff * 5);
    float  e0B = efbase[(size_t)pairoff * 5 + 4];
    edge_stage_a(w1f, e0A, e0B, q, n, xb0);

    // prefetch iter 1 EF
    float4 evA1; float evB1;
    {
        const float* p = efbase + (size_t)(64 + pairoff) * 5;
        evA1 = *(const float4*)p;
        evB1 = p[4];
    }

    for (int iter = 0; iter < 8; ++iter) {
        // prefetch iter+2 EF
        float4 nxA; float nxB;
        if (iter < 6) {
            const float* p = efbase + (size_t)((iter + 2) * 64 + pairoff) * 5;
            nxA = *(const float4*)p;
            nxB = p[4];
        }
        // stage A for iter+1 -> other buffer (independent of stage B below)
        if (iter < 7)
            edge_stage_a(w1f, evA1, evB1, q, n, ((iter + 1) & 1) ? xb1 : xb0);

        // stage B for iter <- current buffer; split even/odd chains
        char* xr = (iter & 1) ? xb1 : xb0;
        f32x4 aA = {0.f, 0.f, 0.f, 0.f}, aB = {0.f, 0.f, 0.f, 0.f};
        f32x4 sA = {0.f, 0.f, 0.f, 0.f}, sB = {0.f, 0.f, 0.f, 0.f};
#pragma unroll
        for (int kc = 0; kc < 8; kc += 2) {
            short8 a0 = *(const short8*)(xr + n * 528 + kc * 64 + q * 16);
            short8 a1 = *(const short8*)(xr + n * 528 + (kc + 1) * 64 + q * 16);
            aA = __builtin_amdgcn_mfma_f32_16x16x32_bf16(a0, b2f[kc], aA, 0, 0, 0);
            sA = __builtin_amdgcn_mfma_f32_16x16x32_bf16(a0, a0, sA, 0, 0, 0);
            aB = __builtin_amdgcn_mfma_f32_16x16x32_bf16(a1, b2f[kc + 1], aB, 0, 0, 0);
            sB = __builtin_amdgcn_mfma_f32_16x16x32_bf16(a1, a1, sB, 0, 0, 0);
        }
        f32x4 acc, acc2;
#pragma unroll
        for (int r = 0; r < 4; ++r) { acc[r] = aA[r] + aB[r]; acc2[r] = sA[r] + sB[r]; }

        // epilogue: LN fold
        int jb = iter * 64 + wv * 16;
        int base = lane & 48;
        float er[4];
#pragma unroll
        for (int r = 0; r < 4; ++r) {
            float sm = __shfl(acc[r], base + 8);
            float sq = __shfl(acc2[r], base + (base >> 2) + r);
            float dot = acc[r];
            float mu = sm * inv256;
            float var = fmaf(-mu, mu, sq * inv256);
            float rs = rsqrtf(var + 1e-5f);
            er[r] = fmaf(dot - mu * shv, rs, bbv);
        }
        if (n < 8) {
            uint2 outv;
            outv.x = pack_bf16rnd(er[0], er[1]);
            outv.y = pack_bf16rnd(er[2], er[3]);
            size_t basep = (((size_t)(b * NH + n) * L_SEQ + i) * L_SEQ) + jb + q * 4;
            *(uint2*)(E2 + basep) = outv;
        }
        evA1 = nxA; evB1 = nxB;
    }
}

// ---------------------------------------------------------------------------
// attn: unchanged.
// ---------------------------------------------------------------------------
__global__ __launch_bounds__(256, 3) void attn_kernel(
    const float* __restrict__ Q, const float* __restrict__ Kt,
    const float* __restrict__ V, const ushort* __restrict__ E2,
    const int* __restrict__ MSK, float* __restrict__ Y)
{
    __shared__ float stage[4096];       // 16 KB: K chunk [32][128] / V chunk [128][32]
    __shared__ float pbuf[4][4][520];   // per-wave p rows (fp32)
    __shared__ float qs_t[32][16];      // q transposed: [d][row]

    int bh = blockIdx.x;
    int b = bh >> 3, h = bh & 7;
    int tid = threadIdx.x;
    int wv = tid >> 6, lane = tid & 63;
    int i0 = blockIdx.y * 16;
    int i = i0 + wv * 4;

    const float* Ktb = Kt + (size_t)bh * (HD * L_SEQ);
    const float* Vb  = V + (size_t)b * L_SEQ * D_EMB + h * HD;

    size_t erow = ((size_t)bh * L_SEQ + i) * L_SEQ;
    size_t mrow = ((size_t)b * L_SEQ + i) * L_SEQ;

    unsigned int e2p[4][4];
    int2 mkp[4][4];
#pragma unroll
    for (int r = 0; r < 4; ++r)
#pragma unroll
        for (int c = 0; c < 4; ++c) {
            int j = c * 128 + 2 * lane;
            e2p[r][c] = *(const unsigned int*)(E2 + erow + (size_t)r * L_SEQ + j);
            mkp[r][c] = *(const int2*)(MSK + mrow + (size_t)r * L_SEQ + j);
        }

    if (tid < 128) {
        int r = tid >> 3, c4 = (tid & 7) * 4;
        float4 qv = *(const float4*)(Q + ((size_t)(b * L_SEQ + i0 + r)) * 256 + h * HD + c4);
        qs_t[c4 + 0][r] = qv.x; qs_t[c4 + 1][r] = qv.y;
        qs_t[c4 + 2][r] = qv.z; qs_t[c4 + 3][r] = qv.w;
    }

    float s[4][8];
#pragma unroll
    for (int r = 0; r < 4; ++r)
#pragma unroll
        for (int t = 0; t < 8; ++t) s[r][t] = 0.f;

    for (int c = 0; c < 4; ++c) {
        if (c) __syncthreads();
        {
            int d0 = tid >> 5, jj = (tid & 31) * 4;
#pragma unroll
            for (int p = 0; p < 4; ++p) {
                int d = p * 8 + d0;
                float4 kv = *(const float4*)(Ktb + (size_t)d * L_SEQ + c * 128 + jj);
                *(float4*)&stage[d * 128 + jj] = kv;
            }
        }
        __syncthreads();
        int c2 = c * 2;
#pragma unroll 8
        for (int d = 0; d < HD; ++d) {
            float4 q4 = *(const float4*)&qs_t[d][wv * 4];
            float2 kv = *(const float2*)&stage[d * 128 + 2 * lane];
            s[0][c2]     = fmaf(q4.x, kv.x, s[0][c2]);
            s[0][c2 + 1] = fmaf(q4.x, kv.y, s[0][c2 + 1]);
            s[1][c2]     = fmaf(q4.y, kv.x, s[1][c2]);
            s[1][c2 + 1] = fmaf(q4.y, kv.y, s[1][c2 + 1]);
            s[2][c2]     = fmaf(q4.z, kv.x, s[2][c2]);
            s[2][c2 + 1] = fmaf(q4.z, kv.y, s[2][c2 + 1]);
            s[3][c2]     = fmaf(q4.w, kv.x, s[3][c2]);
            s[3][c2 + 1] = fmaf(q4.w, kv.y, s[3][c2 + 1]);
        }
    }

    const float scl = 0.17677669529663687f;  // 1/sqrt(32)
#pragma unroll
    for (int r = 0; r < 4; ++r) {
        float sv[8];
        float m = -3.0e38f;
#pragma unroll
        for (int idx = 0; idx < 8; ++idx) {
            int c = idx >> 1, u = idx & 1;
            unsigned int pk = e2p[r][c];
            float e = bf2f((ushort)(u ? (pk >> 16) : (pk & 0xffff)));
            int mk = u ? mkp[r][c].y : mkp[r][c].x;
            float v = (mk != 0) ? fmaf(s[r][idx], scl, e) : -1e30f;
            sv[idx] = v;
            m = fmaxf(m, v);
        }
#pragma unroll
        for (int o = 32; o > 0; o >>= 1) m = fmaxf(m, __shfl_xor(m, o));
        float ssum = 0.f;
#pragma unroll
        for (int idx = 0; idx < 8; ++idx) {
            float p = __expf(sv[idx] - m);
            sv[idx] = p;
            ssum += p;
        }
#pragma unroll
        for (int o = 32; o > 0; o >>= 1) ssum += __shfl_xor(ssum, o);
        float inv = 1.0f / ssum;
#pragma unroll
        for (int c = 0; c < 4; ++c) {
            float2 w;
            w.x = sv[c * 2] * inv;
            w.y = sv[c * 2 + 1] * inv;
            *(float2*)&pbuf[wv][r][c * 128 + 2 * lane] = w;
        }
    }

    int dg = lane >> 3, js = lane & 7;
    float4 acc[4];
#pragma unroll
    for (int r = 0; r < 4; ++r) { acc[r].x = 0.f; acc[r].y = 0.f; acc[r].z = 0.f; acc[r].w = 0.f; }

    for (int c = 0; c < 4; ++c) {
        __syncthreads();
        {
            int j0 = tid >> 3, dd = (tid & 7) * 4;
#pragma unroll
            for (int p = 0; p < 4; ++p) {
                int j = p * 32 + j0;
                float4 vv = *(const float4*)(Vb + (size_t)(c * 128 + j) * D_EMB + dd);
                *(float4*)&stage[j * 32 + dd] = vv;
            }
        }
        __syncthreads();
#pragma unroll
        for (int jb = 0; jb < 16; ++jb) {
            int jj = jb * 8 + js;
            float4 v4 = *(const float4*)&stage[jj * 32 + dg * 4];
#pragma unroll
            for (int r = 0; r < 4; ++r) {
                float p = pbuf[wv][r][c * 128 + jj];
                acc[r].x = fmaf(p, v4.x, acc[r].x);
                acc[r].y = fmaf(p, v4.y, acc[r].y);
                acc[r].z = fmaf(p, v4.z, acc[r].z);
                acc[r].w = fmaf(p, v4.w, acc[r].w);
            }
        }
    }

#pragma unroll
    for (int off = 1; off < 8; off <<= 1) {
#pragma unroll
        for (int r = 0; r < 4; ++r) {
            acc[r].x += __shfl_xor(acc[r].x, off);
            acc[r].y += __shfl_xor(acc[r].y, off);
            acc[r].z += __shfl_xor(acc[r].z, off);
            acc[r].w += __shfl_xor(acc[r].w, off);
        }
    }
    if (js == 0) {
#pragma unroll
        for (int r = 0; r < 4; ++r)
            *(float4*)(Y + ((size_t)(b * L_SEQ + i + r)) * 256 + h * HD + dg * 4) = acc[r];
    }
}

// ---------------------------------------------------------------------------
extern "C" void kernel_launch(void* const* d_in, const int* in_sizes, int n_in,
                              void* d_out, int out_size, void* d_ws, size_t ws_size,
                              hipStream_t stream)
{
    const float* key   = (const float*)d_in[0];
    const float* value = (const float*)d_in[1];
    const float* query = (const float*)d_in[2];
    const int*   msk   = (const int*)d_in[3];
    const float* ef    = (const float*)d_in[4];
    const float* Wk  = (const float*)d_in[5];  const float* bk  = (const float*)d_in[6];
    const float* Wq  = (const float*)d_in[7];  const float* bq  = (const float*)d_in[8];
    const float* Wv  = (const float*)d_in[9];  const float* bv  = (const float*)d_in[10];
    const float* Wp  = (const float*)d_in[11]; const float* bp  = (const float*)d_in[12];
    const float* We1 = (const float*)d_in[13]; const float* be1 = (const float*)d_in[14];
    const float* lng = (const float*)d_in[15]; const float* lnb = (const float*)d_in[16];
    const float* We2 = (const float*)d_in[17]; const float* be2 = (const float*)d_in[18];

    const int MTOK = 4 * L_SEQ;          // 2048 rows
    const int NELT = MTOK * D_EMB;       // 524288

    float* ws    = (float*)d_ws;
    float* Qw    = ws;
    float* Vw    = Qw + NELT;
    float* Yw    = Vw + NELT;
    float* Ktw   = Yw + NELT;
    ushort* W1G  = (ushort*)(Ktw + NELT);   // 8192 bf16
    ushort* B2G  = W1G + 8192;              // 4096 bf16
    float* tail  = (float*)(B2G + 4096);    // 32 floats
    ushort* WThi = (ushort*)(tail + 32);    // 4*65536 bf16 (512 KB)
    ushort* WTlo = WThi + 4 * 65536;        // 4*65536 bf16 (512 KB)
    ushort* E2   = WTlo + 4 * 65536;        // 8388608 bf16 (~16.8 MB)

    hipLaunchKernelGGL(prep_kernel, dim3(65), dim3(256), 0, stream,
                       We1, be1, lng, lnb, We2, be2,
                       Wq, Wk, Wv, Wp,
                       W1G, B2G, tail, WThi, WTlo);
    hipLaunchKernelGGL(gemm_mfma, dim3(32, 4, 3), dim3(256), 0, stream,
                       query, WThi + 0 * 65536, WTlo + 0 * 65536, bq, Qw,  (float*)nullptr,
                       key,   WThi + 1 * 65536, WTlo + 1 * 65536, bk, (float*)nullptr, Ktw,
                       value, WThi + 2 * 65536, WTlo + 2 * 65536, bv, Vw,  (float*)nullptr);
    hipLaunchKernelGGL(edge_bias_mfma, dim3(2048), dim3(256), 0, stream,
                       ef, W1G, B2G, tail, E2);
    hipLaunchKernelGGL(attn_kernel, dim3(32, 32), dim3(256), 0, stream,
                       Qw, Ktw, Vw, E2, msk, Yw);
    hipLaunchKernelGGL(gemm_mfma, dim3(32, 4, 1), dim3(256), 0, stream,
                       Yw, WThi + 3 * 65536, WTlo + 3 * 65536, bp, (float*)d_out, (float*)nullptr,
                       Yw, WThi + 3 * 65536, WTlo + 3 * 65536, bp, (float*)d_out, (float*)nullptr,
                       Yw, WThi + 3 * 65536, WTlo + 3 * 65536, bp, (float*)d_out, (float*)nullptr);
}

// Round 9
// 231.460 us; speedup vs baseline: 1.0275x; 1.0275x over previous
//
#include <hip/hip_runtime.h>
#include <hip/hip_bf16.h>

#define L_SEQ 512
#define D_EMB 256
#define NH 8
#define HD 32
#define LL (L_SEQ * L_SEQ)   // 262144

typedef __attribute__((ext_vector_type(8))) short short8;
typedef __attribute__((ext_vector_type(4))) float f32x4;
typedef unsigned short ushort;

__device__ __forceinline__ float bf2f(ushort u) {
    unsigned int x = ((unsigned int)u) << 16;
    float f;
    __builtin_memcpy(&f, &x, 4);
    return f;
}
__device__ __forceinline__ ushort f2bf(float x) {   // RNE (host-quality), prep only
    __hip_bfloat16 h = __float2bfloat16(x);
    ushort u;
    __builtin_memcpy(&u, &h, 2);
    return u;
}
__device__ __forceinline__ unsigned int fbits(float x) {
    unsigned int u;
    __builtin_memcpy(&u, &x, 4);
    return u;
}
__device__ __forceinline__ float asf(unsigned int u) {
    float f;
    __builtin_memcpy(&f, &u, 4);
    return f;
}
// pack bf16(a) | bf16(b)<<16, nearest-ties-away rounding, 3 VALU ops
__device__ __forceinline__ unsigned int pack_bf16rnd(float a, float b) {
    return __builtin_amdgcn_perm(fbits(b) + 0x8000u, fbits(a) + 0x8000u, 0x07060302u);
}
// hi16(x) | hi16(y)<<16  (one v_perm)
__device__ __forceinline__ unsigned int packhi(unsigned int y, unsigned int x) {
    return __builtin_amdgcn_perm(y, x, 0x07060302u);
}
// hi/lo split of two floats: .x = packed hi pair, .y = packed lo pair
__device__ __forceinline__ uint2 cvt_hilo2(float v0, float v1) {
    unsigned int hi = pack_bf16rnd(v0, v1);
    float h0 = asf(hi << 16);
    float h1 = asf(hi & 0xffff0000u);
    unsigned int lo = pack_bf16rnd(v0 - h0, v1 - h1);
    uint2 r; r.x = hi; r.y = lo;
    return r;
}

// ---------------------------------------------------------------------------
// prep (merged): block 0 builds the edge-kernel tables; blocks 1..64 do the
// projection-weight transpose+hi/lo-split.
// W1G row permutation: tile t, A-row m -> physical d = (m>>2)*64+t*4+(m&3)
// so stage-A's per-lane outputs (d = q*64+t*4+r) are LDS-contiguous.
// ---------------------------------------------------------------------------
__global__ __launch_bounds__(256) void prep_kernel(
    const float* __restrict__ We1, const float* __restrict__ be1,
    const float* __restrict__ g,   const float* __restrict__ bta,
    const float* __restrict__ We2, const float* __restrict__ be2,
    const float* __restrict__ Wq, const float* __restrict__ Wk,
    const float* __restrict__ Wv, const float* __restrict__ Wp,
    ushort* __restrict__ W1G, ushort* __restrict__ B2G, float* __restrict__ tail,
    ushort* __restrict__ WThi, ushort* __restrict__ WTlo)
{
    int t = threadIdx.x;  // 0..255
    if (blockIdx.x != 0) {
        int bx = blockIdx.x - 1;
        int w = bx >> 4, ny = bx & 15;
        const float* W = (w == 0) ? Wq : (w == 1) ? Wk : (w == 2) ? Wv : Wp;
        ushort* dh = WThi + (size_t)w * 65536;
        ushort* dl = WTlo + (size_t)w * 65536;
        int n = ny * 16 + (t >> 4);
        int k0 = (t & 15) * 16;
        ushort hbuf[16], lbuf[16];
#pragma unroll
        for (int kk = 0; kk < 16; ++kk) {
            float v = W[(size_t)(k0 + kk) * 256 + n];
            unsigned int hb = fbits(v) + 0x8000u;
            ushort hi = (ushort)(hb >> 16);
            float res = v - bf2f(hi);
            hbuf[kk] = hi;
            lbuf[kk] = (ushort)((fbits(res) + 0x8000u) >> 16);
        }
        *(short8*)(dh + (size_t)n * 256 + k0)     = *(short8*)&hbuf[0];
        *(short8*)(dh + (size_t)n * 256 + k0 + 8) = *(short8*)&hbuf[8];
        *(short8*)(dl + (size_t)n * 256 + k0)     = *(short8*)&lbuf[0];
        *(short8*)(dl + (size_t)n * 256 + k0 + 8) = *(short8*)&lbuf[8];
        return;
    }

    __shared__ float red[16][256];
    float gd = g[t], bd = bta[t];
#pragma unroll
    for (int h = 0; h < 8; ++h) {
        float w2 = We2[t * 8 + h];
        red[h][t] = gd * w2;
        red[8 + h][t] = bd * w2;
    }
    __syncthreads();
    for (int off = 128; off > 0; off >>= 1) {
        if (t < off) {
#pragma unroll
            for (int row = 0; row < 16; ++row) red[row][t] += red[row][t + off];
        }
        __syncthreads();
    }
    if (t < 8) {
        tail[t] = red[t][0];
        tail[8 + t] = red[8 + t][0] + be2[t];
    }
    if (t >= 16 && t < 32) tail[t] = 0.f;

    for (int idx = t; idx < 8192; idx += 256) {
        int j = idx & 7, lane = (idx >> 3) & 63, tile = idx >> 9;
        int m = lane & 15, q = lane >> 4;
        int k = q * 8 + j;
        int d = (m >> 2) * 64 + tile * 4 + (m & 3);   // permuted
        float v = 0.f;
        bool lo = false;
        if (k < 5)        v = We1[k * 256 + d];
        else if (k < 10)  { v = We1[(k - 5) * 256 + d]; lo = true; }
        else if (k < 15)  v = We1[(k - 10) * 256 + d];
        else if (k == 15) v = be1[d];
        else if (k == 16) { v = be1[d]; lo = true; }
        ushort hi = f2bf(v);
        W1G[idx] = lo ? f2bf(v - bf2f(hi)) : hi;
    }
    for (int idx = t; idx < 4096; idx += 256) {
        int j = idx & 7, lane = (idx >> 3) & 63, kc = idx >> 9;
        int n = lane & 15, q = lane >> 4;
        int d = kc * 32 + q * 8 + j;
        ushort out;
        if (n < 8)       out = f2bf(g[d] * We2[d * 8 + n]);
        else if (n == 8) out = 0x3F80;   // 1.0 bf16
        else             out = 0;
        B2G[idx] = out;
    }
}

// ---------------------------------------------------------------------------
// gemm_mfma: C[2048,256] = A @ W + bias (fp32-accurate via bf16 hi/lo).
// If Ct != null, write the (per b,h) transposed layout instead (K -> Kt).
// ---------------------------------------------------------------------------
__global__ __launch_bounds__(256) void gemm_mfma(
    const float* __restrict__ A0, const ushort* __restrict__ H0,
    const ushort* __restrict__ L0, const float* __restrict__ b0,
    float* __restrict__ C0, float* __restrict__ T0,
    const float* __restrict__ A1, const ushort* __restrict__ H1,
    const ushort* __restrict__ L1, const float* __restrict__ b1,
    float* __restrict__ C1, float* __restrict__ T1,
    const float* __restrict__ A2, const ushort* __restrict__ H2,
    const ushort* __restrict__ L2, const float* __restrict__ b2,
    float* __restrict__ C2, float* __restrict__ T2)
{
    const float* A; const ushort* BH; const ushort* BL;
    const float* bias; float* C; float* Ct;
    if (blockIdx.z == 0)      { A = A0; BH = H0; BL = L0; bias = b0; C = C0; Ct = T0; }
    else if (blockIdx.z == 1) { A = A1; BH = H1; BL = L1; bias = b1; C = C1; Ct = T1; }
    else                      { A = A2; BH = H2; BL = L2; bias = b2; C = C2; Ct = T2; }

    __shared__ ushort Ahi[64][40];
    __shared__ ushort Alo[64][40];

    int tid = threadIdx.x;
    int wv = tid >> 6, lane = tid & 63;
    int m = lane & 15, quad = lane >> 4;
    int bm = blockIdx.x * 64, bn = blockIdx.y * 64;

    int sm = tid >> 2, sg = (tid & 3) * 8;
    const float* Arow = A + (size_t)(bm + sm) * 256 + sg;

    int nrow = bn + wv * 16 + m;
    const ushort* bhp = BH + (size_t)nrow * 256 + quad * 8;
    const ushort* blp = BL + (size_t)nrow * 256 + quad * 8;

    f32x4 acc[4];
#pragma unroll
    for (int mt = 0; mt < 4; ++mt) acc[mt] = (f32x4){0.f, 0.f, 0.f, 0.f};

    for (int k0 = 0; k0 < 256; k0 += 32) {
        float4 a0 = *(const float4*)(Arow + k0);
        float4 a1 = *(const float4*)(Arow + k0 + 4);
        uint2 c0 = cvt_hilo2(a0.x, a0.y);
        uint2 c1 = cvt_hilo2(a0.z, a0.w);
        uint2 c2 = cvt_hilo2(a1.x, a1.y);
        uint2 c3 = cvt_hilo2(a1.z, a1.w);
        if (k0) __syncthreads();
        uint4 hq; hq.x = c0.x; hq.y = c1.x; hq.z = c2.x; hq.w = c3.x;
        uint4 lq; lq.x = c0.y; lq.y = c1.y; lq.z = c2.y; lq.w = c3.y;
        *(uint4*)&Ahi[sm][sg] = hq;
        *(uint4*)&Alo[sm][sg] = lq;
        __syncthreads();

        short8 bhi = *(const short8*)(bhp + k0);
        short8 blo = *(const short8*)(blp + k0);
#pragma unroll
        for (int mt = 0; mt < 4; ++mt) {
            short8 ahi = *(const short8*)&Ahi[mt * 16 + m][quad * 8];
            short8 alo = *(const short8*)&Alo[mt * 16 + m][quad * 8];
            acc[mt] = __builtin_amdgcn_mfma_f32_16x16x32_bf16(ahi, blo, acc[mt], 0, 0, 0);
            acc[mt] = __builtin_amdgcn_mfma_f32_16x16x32_bf16(alo, bhi, acc[mt], 0, 0, 0);
            acc[mt] = __builtin_amdgcn_mfma_f32_16x16x32_bf16(ahi, bhi, acc[mt], 0, 0, 0);
        }
    }

    float bn_bias = bias[nrow];
    if (Ct) {
        int bb = bm >> 9, l0 = bm & 511;
        float* outp = Ct + ((size_t)(bb * 256 + nrow)) * 512 + l0 + quad * 4;
#pragma unroll
        for (int mt = 0; mt < 4; ++mt) {
            float4 o;
            o.x = acc[mt][0] + bn_bias; o.y = acc[mt][1] + bn_bias;
            o.z = acc[mt][2] + bn_bias; o.w = acc[mt][3] + bn_bias;
            *(float4*)(outp + mt * 16) = o;
        }
    } else {
#pragma unroll
        for (int mt = 0; mt < 4; ++mt) {
#pragma unroll
            for (int r = 0; r < 4; ++r) {
                C[(size_t)(bm + mt * 16 + quad * 4 + r) * 256 + nrow] = acc[mt][r] + bn_bias;
            }
        }
    }
}

// ---------------------------------------------------------------------------
// edge_bias_mfma v5: v3 structure (single X buffer, serial iters) but
// re-partitioned to 128-thread blocks (2 independent waves; edge waves never
// sync). LDS/block 33.8 -> 16.9 KB => ~2x resident waves/CU for latency
// hiding. Math bit-identical to v3. Block = (row, j-half): 4096 blocks.
// ---------------------------------------------------------------------------
__global__ __launch_bounds__(128) void edge_bias_mfma(
    const float* __restrict__ EF, const ushort* __restrict__ W1G,
    const ushort* __restrict__ B2G, const float* __restrict__ tail,
    ushort* __restrict__ E2)
{
    __shared__ __align__(16) char xt[2 * 16 * 528];  // 16896 B, per-wave tiles
    int tid = threadIdx.x;
    int wv = tid >> 6, lane = tid & 63;
    int q = lane >> 4, n = lane & 15;
    char* myx = xt + wv * (16 * 528);

    int bi2 = blockIdx.x;           // (b*512 + i) * 2 + half
    int row = bi2 >> 1, half = bi2 & 1;
    int b = row >> 9, i = row & 511;
    size_t rowbase = (size_t)row * 512;

    short8 w1f[16];
#pragma unroll
    for (int t = 0; t < 16; ++t)
        w1f[t] = *(const short8*)(W1G + (t * 64 + lane) * 8);
    short8 b2f[8];
#pragma unroll
    for (int kc = 0; kc < 8; ++kc)
        b2f[kc] = *(const short8*)(B2G + (kc * 64 + lane) * 8);

    float shv = tail[n];
    float bbv = tail[8 + n];
    const float inv256 = 1.0f / 256.0f;

    const float* efbase = EF + rowbase * 5;
    int pairoff = half * 256 + wv * 16 + n;   // this lane's pair within iter 0

    // prefetch iter 0
    float4 evA = *(const float4*)(efbase + (size_t)pairoff * 5);
    float  evB = efbase[(size_t)pairoff * 5 + 4];

    for (int iter = 0; iter < 8; ++iter) {
        // prefetch next iter's EF while computing this one
        float4 nA; float nB;
        if (iter < 7) {
            const float* p = efbase + (size_t)((iter + 1) * 32 + pairoff) * 5;
            nA = *(const float4*)p;
            nB = p[4];
        }
        int jb = half * 256 + iter * 32 + wv * 16;

        unsigned int hb[5], la[5];
        hb[0] = fbits(evA.x); hb[1] = fbits(evA.y); hb[2] = fbits(evA.z);
        hb[3] = fbits(evA.w); hb[4] = fbits(evB);
        {
            float e0 = evA.x - asf(hb[0] & 0xffff0000u);
            float e1 = evA.y - asf(hb[1] & 0xffff0000u);
            float e2 = evA.z - asf(hb[2] & 0xffff0000u);
            float e3 = evA.w - asf(hb[3] & 0xffff0000u);
            float e4 = evB   - asf(hb[4] & 0xffff0000u);
            la[0] = fbits(e0) + 0x8000u;
            la[1] = fbits(e1) + 0x8000u;
            la[2] = fbits(e2) + 0x8000u;
            la[3] = fbits(e3) + 0x8000u;
            la[4] = fbits(e4) + 0x8000u;
        }
        // q==0 dwords: [h0|h1, h2|h3, h4|h0, h1|h2]; q==1: [h3|h4, l0|l1, l2|l3, l4|ONE]
        unsigned int A0v = packhi(hb[1], hb[0]);
        unsigned int A1v = packhi(hb[3], hb[2]);
        unsigned int A2v = packhi(hb[0], hb[4]);
        unsigned int A3v = packhi(hb[2], hb[1]);
        unsigned int B0v = packhi(hb[4], hb[3]);
        unsigned int B1v = packhi(la[1], la[0]);
        unsigned int B2v = packhi(la[3], la[2]);
        unsigned int B3v = packhi(0x3F800000u, la[4]);
        uint4 efd;
        bool isq0 = (q == 0), isq1 = (q == 1), isq2 = (q == 2);
        efd.x = isq0 ? A0v : isq1 ? B0v : isq2 ? 0x3F80u : 0u;
        efd.y = isq0 ? A1v : isq1 ? B1v : 0u;
        efd.z = isq0 ? A2v : isq1 ? B2v : 0u;
        efd.w = isq0 ? A3v : isq1 ? B3v : 0u;
        short8 ef8;
        __builtin_memcpy(&ef8, &efd, 16);

        // ---- Stage A: X tiles -> LDS (bf16), b128 writes every 2 tiles
        unsigned int pk0 = 0, pk1 = 0;
#pragma unroll
        for (int t = 0; t < 16; ++t) {
            f32x4 z = {0.f, 0.f, 0.f, 0.f};
            f32x4 d1 = __builtin_amdgcn_mfma_f32_16x16x32_bf16(w1f[t], ef8, z, 0, 0, 0);
            float x0 = fmaxf(d1[0], 0.f);
            float x1 = fmaxf(d1[1], 0.f);
            float x2 = fmaxf(d1[2], 0.f);
            float x3 = fmaxf(d1[3], 0.f);
            unsigned int pa = pack_bf16rnd(x0, x1);
            unsigned int pb = pack_bf16rnd(x2, x3);
            if (t & 1) {
                uint4 wq; wq.x = pk0; wq.y = pk1; wq.z = pa; wq.w = pb;
                *(uint4*)(myx + n * 528 + q * 128 + (t - 1) * 8) = wq;
            } else {
                pk0 = pa; pk1 = pb;
            }
        }

        // ---- Stage B: dots+sum via B2, sumsq via X X^T (split chains)
        f32x4 aA = {0.f, 0.f, 0.f, 0.f}, aB = {0.f, 0.f, 0.f, 0.f};
        f32x4 sA = {0.f, 0.f, 0.f, 0.f}, sB = {0.f, 0.f, 0.f, 0.f};
#pragma unroll
        for (int kc = 0; kc < 8; kc += 2) {
            short8 a0 = *(const short8*)(myx + n * 528 + kc * 64 + q * 16);
            short8 a1 = *(const short8*)(myx + n * 528 + (kc + 1) * 64 + q * 16);
            aA = __builtin_amdgcn_mfma_f32_16x16x32_bf16(a0, b2f[kc], aA, 0, 0, 0);
            sA = __builtin_amdgcn_mfma_f32_16x16x32_bf16(a0, a0, sA, 0, 0, 0);
            aB = __builtin_amdgcn_mfma_f32_16x16x32_bf16(a1, b2f[kc + 1], aB, 0, 0, 0);
            sB = __builtin_amdgcn_mfma_f32_16x16x32_bf16(a1, a1, sB, 0, 0, 0);
        }
        f32x4 acc, acc2;
#pragma unroll
        for (int r = 0; r < 4; ++r) { acc[r] = aA[r] + aB[r]; acc2[r] = sA[r] + sB[r]; }

        // ---- Epilogue: LN fold
        int base = lane & 48;
        float er[4];
#pragma unroll
        for (int r = 0; r < 4; ++r) {
            float sm = __shfl(acc[r], base + 8);
            float sq = __shfl(acc2[r], base + (base >> 2) + r);
            float dot = acc[r];
            float mu = sm * inv256;
            float var = fmaf(-mu, mu, sq * inv256);
            float rs = rsqrtf(var + 1e-5f);
            er[r] = fmaf(dot - mu * shv, rs, bbv);
        }
        if (n < 8) {
            uint2 outv;
            outv.x = pack_bf16rnd(er[0], er[1]);
            outv.y = pack_bf16rnd(er[2], er[3]);
            size_t basep = (((size_t)(b * NH + n) * L_SEQ + i) * L_SEQ) + jb + q * 4;
            *(uint2*)(E2 + basep) = outv;
        }
        evA = nA; evB = nB;
    }
}

// ---------------------------------------------------------------------------
// attn: unchanged.
// ---------------------------------------------------------------------------
__global__ __launch_bounds__(256, 3) void attn_kernel(
    const float* __restrict__ Q, const float* __restrict__ Kt,
    const float* __restrict__ V, const ushort* __restrict__ E2,
    const int* __restrict__ MSK, float* __restrict__ Y)
{
    __shared__ float stage[4096];       // 16 KB: K chunk [32][128] / V chunk [128][32]
    __shared__ float pbuf[4][4][520];   // per-wave p rows (fp32)
    __shared__ float qs_t[32][16];      // q transposed: [d][row]

    int bh = blockIdx.x;
    int b = bh >> 3, h = bh & 7;
    int tid = threadIdx.x;
    int wv = tid >> 6, lane = tid & 63;
    int i0 = blockIdx.y * 16;
    int i = i0 + wv * 4;

    const float* Ktb = Kt + (size_t)bh * (HD * L_SEQ);
    const float* Vb  = V + (size_t)b * L_SEQ * D_EMB + h * HD;

    size_t erow = ((size_t)bh * L_SEQ + i) * L_SEQ;
    size_t mrow = ((size_t)b * L_SEQ + i) * L_SEQ;

    unsigned int e2p[4][4];
    int2 mkp[4][4];
#pragma unroll
    for (int r = 0; r < 4; ++r)
#pragma unroll
        for (int c = 0; c < 4; ++c) {
            int j = c * 128 + 2 * lane;
            e2p[r][c] = *(const unsigned int*)(E2 + erow + (size_t)r * L_SEQ + j);
            mkp[r][c] = *(const int2*)(MSK + mrow + (size_t)r * L_SEQ + j);
        }

    if (tid < 128) {
        int r = tid >> 3, c4 = (tid & 7) * 4;
        float4 qv = *(const float4*)(Q + ((size_t)(b * L_SEQ + i0 + r)) * 256 + h * HD + c4);
        qs_t[c4 + 0][r] = qv.x; qs_t[c4 + 1][r] = qv.y;
        qs_t[c4 + 2][r] = qv.z; qs_t[c4 + 3][r] = qv.w;
    }

    float s[4][8];
#pragma unroll
    for (int r = 0; r < 4; ++r)
#pragma unroll
        for (int t = 0; t < 8; ++t) s[r][t] = 0.f;

    for (int c = 0; c < 4; ++c) {
        if (c) __syncthreads();
        {
            int d0 = tid >> 5, jj = (tid & 31) * 4;
#pragma unroll
            for (int p = 0; p < 4; ++p) {
                int d = p * 8 + d0;
                float4 kv = *(const float4*)(Ktb + (size_t)d * L_SEQ + c * 128 + jj);
                *(float4*)&stage[d * 128 + jj] = kv;
            }
        }
        __syncthreads();
        int c2 = c * 2;
#pragma unroll 8
        for (int d = 0; d < HD; ++d) {
            float4 q4 = *(const float4*)&qs_t[d][wv * 4];
            float2 kv = *(const float2*)&stage[d * 128 + 2 * lane];
            s[0][c2]     = fmaf(q4.x, kv.x, s[0][c2]);
            s[0][c2 + 1] = fmaf(q4.x, kv.y, s[0][c2 + 1]);
            s[1][c2]     = fmaf(q4.y, kv.x, s[1][c2]);
            s[1][c2 + 1] = fmaf(q4.y, kv.y, s[1][c2 + 1]);
            s[2][c2]     = fmaf(q4.z, kv.x, s[2][c2]);
            s[2][c2 + 1] = fmaf(q4.z, kv.y, s[2][c2 + 1]);
            s[3][c2]     = fmaf(q4.w, kv.x, s[3][c2]);
            s[3][c2 + 1] = fmaf(q4.w, kv.y, s[3][c2 + 1]);
        }
    }

    const float scl = 0.17677669529663687f;  // 1/sqrt(32)
#pragma unroll
    for (int r = 0; r < 4; ++r) {
        float sv[8];
        float m = -3.0e38f;
#pragma unroll
        for (int idx = 0; idx < 8; ++idx) {
            int c = idx >> 1, u = idx & 1;
            unsigned int pk = e2p[r][c];
            float e = bf2f((ushort)(u ? (pk >> 16) : (pk & 0xffff)));
            int mk = u ? mkp[r][c].y : mkp[r][c].x;
            float v = (mk != 0) ? fmaf(s[r][idx], scl, e) : -1e30f;
            sv[idx] = v;
            m = fmaxf(m, v);
        }
#pragma unroll
        for (int o = 32; o > 0; o >>= 1) m = fmaxf(m, __shfl_xor(m, o));
        float ssum = 0.f;
#pragma unroll
        for (int idx = 0; idx < 8; ++idx) {
            float p = __expf(sv[idx] - m);
            sv[idx] = p;
            ssum += p;
        }
#pragma unroll
        for (int o = 32; o > 0; o >>= 1) ssum += __shfl_xor(ssum, o);
        float inv = 1.0f / ssum;
#pragma unroll
        for (int c = 0; c < 4; ++c) {
            float2 w;
            w.x = sv[c * 2] * inv;
            w.y = sv[c * 2 + 1] * inv;
            *(float2*)&pbuf[wv][r][c * 128 + 2 * lane] = w;
        }
    }

    int dg = lane >> 3, js = lane & 7;
    float4 acc[4];
#pragma unroll
    for (int r = 0; r < 4; ++r) { acc[r].x = 0.f; acc[r].y = 0.f; acc[r].z = 0.f; acc[r].w = 0.f; }

    for (int c = 0; c < 4; ++c) {
        __syncthreads();
        {
            int j0 = tid >> 3, dd = (tid & 7) * 4;
#pragma unroll
            for (int p = 0; p < 4; ++p) {
                int j = p * 32 + j0;
                float4 vv = *(const float4*)(Vb + (size_t)(c * 128 + j) * D_EMB + dd);
                *(float4*)&stage[j * 32 + dd] = vv;
            }
        }
        __syncthreads();
#pragma unroll
        for (int jb = 0; jb < 16; ++jb) {
            int jj = jb * 8 + js;
            float4 v4 = *(const float4*)&stage[jj * 32 + dg * 4];
#pragma unroll
            for (int r = 0; r < 4; ++r) {
                float p = pbuf[wv][r][c * 128 + jj];
                acc[r].x = fmaf(p, v4.x, acc[r].x);
                acc[r].y = fmaf(p, v4.y, acc[r].y);
                acc[r].z = fmaf(p, v4.z, acc[r].z);
                acc[r].w = fmaf(p, v4.w, acc[r].w);
            }
        }
    }

#pragma unroll
    for (int off = 1; off < 8; off <<= 1) {
#pragma unroll
        for (int r = 0; r < 4; ++r) {
            acc[r].x += __shfl_xor(acc[r].x, off);
            acc[r].y += __shfl_xor(acc[r].y, off);
            acc[r].z += __shfl_xor(acc[r].z, off);
            acc[r].w += __shfl_xor(acc[r].w, off);
        }
    }
    if (js == 0) {
#pragma unroll
        for (int r = 0; r < 4; ++r)
            *(float4*)(Y + ((size_t)(b * L_SEQ + i + r)) * 256 + h * HD + dg * 4) = acc[r];
    }
}

// ---------------------------------------------------------------------------
extern "C" void kernel_launch(void* const* d_in, const int* in_sizes, int n_in,
                              void* d_out, int out_size, void* d_ws, size_t ws_size,
                              hipStream_t stream)
{
    const float* key   = (const float*)d_in[0];
    const float* value = (const float*)d_in[1];
    const float* query = (const float*)d_in[2];
    const int*   msk   = (const int*)d_in[3];
    const float* ef    = (const float*)d_in[4];
    const float* Wk  = (const float*)d_in[5];  const float* bk  = (const float*)d_in[6];
    const float* Wq  = (const float*)d_in[7];  const float* bq  = (const float*)d_in[8];
    const float* Wv  = (const float*)d_in[9];  const float* bv  = (const float*)d_in[10];
    const float* Wp  = (const float*)d_in[11]; const float* bp  = (const float*)d_in[12];
    const float* We1 = (const float*)d_in[13]; const float* be1 = (const float*)d_in[14];
    const float* lng = (const float*)d_in[15]; const float* lnb = (const float*)d_in[16];
    const float* We2 = (const float*)d_in[17]; const float* be2 = (const float*)d_in[18];

    const int MTOK = 4 * L_SEQ;          // 2048 rows
    const int NELT = MTOK * D_EMB;       // 524288

    float* ws    = (float*)d_ws;
    float* Qw    = ws;
    float* Vw    = Qw + NELT;
    float* Yw    = Vw + NELT;
    float* Ktw   = Yw + NELT;
    ushort* W1G  = (ushort*)(Ktw + NELT);   // 8192 bf16
    ushort* B2G  = W1G + 8192;              // 4096 bf16
    float* tail  = (float*)(B2G + 4096);    // 32 floats
    ushort* WThi = (ushort*)(tail + 32);    // 4*65536 bf16 (512 KB)
    ushort* WTlo = WThi + 4 * 65536;        // 4*65536 bf16 (512 KB)
    ushort* E2   = WTlo + 4 * 65536;        // 8388608 bf16 (~16.8 MB)

    hipLaunchKernelGGL(prep_kernel, dim3(65), dim3(256), 0, stream,
                       We1, be1, lng, lnb, We2, be2,
                       Wq, Wk, Wv, Wp,
                       W1G, B2G, tail, WThi, WTlo);
    hipLaunchKernelGGL(gemm_mfma, dim3(32, 4, 3), dim3(256), 0, stream,
                       query, WThi + 0 * 65536, WTlo + 0 * 65536, bq, Qw,  (float*)nullptr,
                       key,   WThi + 1 * 65536, WTlo + 1 * 65536, bk, (float*)nullptr, Ktw,
                       value, WThi + 2 * 65536, WTlo + 2 * 65536, bv, Vw,  (float*)nullptr);
    hipLaunchKernelGGL(edge_bias_mfma, dim3(4096), dim3(128), 0, stream,
                       ef, W1G, B2G, tail, E2);
    hipLaunchKernelGGL(attn_kernel, dim3(32, 32), dim3(256), 0, stream,
                       Qw, Ktw, Vw, E2, msk, Yw);
    hipLaunchKernelGGL(gemm_mfma, dim3(32, 4, 1), dim3(256), 0, stream,
                       Yw, WThi + 3 * 65536, WTlo + 3 * 65536, bp, (float*)d_out, (float*)nullptr,
                       Yw, WThi + 3 * 65536, WTlo + 3 * 65536, bp, (float*)d_out, (float*)nullptr,
                       Yw, WThi + 3 * 65536, WTlo + 3 * 65536, bp, (float*)d_out, (float*)nullptr);
}

// Round 10
// 225.780 us; speedup vs baseline: 1.0534x; 1.0252x over previous
//
#include <hip/hip_runtime.h>
#include <hip/hip_bf16.h>

#define L_SEQ 512
#define D_EMB 256
#define NH 8
#define HD 32
#define LL (L_SEQ * L_SEQ)   // 262144

typedef __attribute__((ext_vector_type(8))) short short8;
typedef __attribute__((ext_vector_type(4))) float f32x4;
typedef unsigned short ushort;

__device__ __forceinline__ float bf2f(ushort u) {
    unsigned int x = ((unsigned int)u) << 16;
    float f;
    __builtin_memcpy(&f, &x, 4);
    return f;
}
__device__ __forceinline__ ushort f2bf(float x) {   // RNE (host-quality), prep only
    __hip_bfloat16 h = __float2bfloat16(x);
    ushort u;
    __builtin_memcpy(&u, &h, 2);
    return u;
}
__device__ __forceinline__ unsigned int fbits(float x) {
    unsigned int u;
    __builtin_memcpy(&u, &x, 4);
    return u;
}
__device__ __forceinline__ float asf(unsigned int u) {
    float f;
    __builtin_memcpy(&f, &u, 4);
    return f;
}
// pack bf16(a) | bf16(b)<<16, nearest-ties-away rounding, 3 VALU ops
__device__ __forceinline__ unsigned int pack_bf16rnd(float a, float b) {
    return __builtin_amdgcn_perm(fbits(b) + 0x8000u, fbits(a) + 0x8000u, 0x07060302u);
}
// hi16(x) | hi16(y)<<16  (one v_perm)
__device__ __forceinline__ unsigned int packhi(unsigned int y, unsigned int x) {
    return __builtin_amdgcn_perm(y, x, 0x07060302u);
}
// hi/lo split of two floats: .x = packed hi pair, .y = packed lo pair
__device__ __forceinline__ uint2 cvt_hilo2(float v0, float v1) {
    unsigned int hi = pack_bf16rnd(v0, v1);
    float h0 = asf(hi << 16);
    float h1 = asf(hi & 0xffff0000u);
    unsigned int lo = pack_bf16rnd(v0 - h0, v1 - h1);
    uint2 r; r.x = hi; r.y = lo;
    return r;
}

// ---------------------------------------------------------------------------
// prep (merged): block 0 builds the edge-kernel tables; blocks 1..64 do the
// projection-weight transpose+hi/lo-split.
// W1G row permutation: tile t, A-row m -> physical d = (m>>2)*64+t*4+(m&3)
// so stage-A's per-lane outputs (d = q*64+t*4+r) are LDS-contiguous.
// ---------------------------------------------------------------------------
__global__ __launch_bounds__(256) void prep_kernel(
    const float* __restrict__ We1, const float* __restrict__ be1,
    const float* __restrict__ g,   const float* __restrict__ bta,
    const float* __restrict__ We2, const float* __restrict__ be2,
    const float* __restrict__ Wq, const float* __restrict__ Wk,
    const float* __restrict__ Wv, const float* __restrict__ Wp,
    ushort* __restrict__ W1G, ushort* __restrict__ B2G, float* __restrict__ tail,
    ushort* __restrict__ WThi, ushort* __restrict__ WTlo)
{
    int t = threadIdx.x;  // 0..255
    if (blockIdx.x != 0) {
        int bx = blockIdx.x - 1;
        int w = bx >> 4, ny = bx & 15;
        const float* W = (w == 0) ? Wq : (w == 1) ? Wk : (w == 2) ? Wv : Wp;
        ushort* dh = WThi + (size_t)w * 65536;
        ushort* dl = WTlo + (size_t)w * 65536;
        int n = ny * 16 + (t >> 4);
        int k0 = (t & 15) * 16;
        ushort hbuf[16], lbuf[16];
#pragma unroll
        for (int kk = 0; kk < 16; ++kk) {
            float v = W[(size_t)(k0 + kk) * 256 + n];
            unsigned int hb = fbits(v) + 0x8000u;
            ushort hi = (ushort)(hb >> 16);
            float res = v - bf2f(hi);
            hbuf[kk] = hi;
            lbuf[kk] = (ushort)((fbits(res) + 0x8000u) >> 16);
        }
        *(short8*)(dh + (size_t)n * 256 + k0)     = *(short8*)&hbuf[0];
        *(short8*)(dh + (size_t)n * 256 + k0 + 8) = *(short8*)&hbuf[8];
        *(short8*)(dl + (size_t)n * 256 + k0)     = *(short8*)&lbuf[0];
        *(short8*)(dl + (size_t)n * 256 + k0 + 8) = *(short8*)&lbuf[8];
        return;
    }

    __shared__ float red[16][256];
    float gd = g[t], bd = bta[t];
#pragma unroll
    for (int h = 0; h < 8; ++h) {
        float w2 = We2[t * 8 + h];
        red[h][t] = gd * w2;
        red[8 + h][t] = bd * w2;
    }
    __syncthreads();
    for (int off = 128; off > 0; off >>= 1) {
        if (t < off) {
#pragma unroll
            for (int row = 0; row < 16; ++row) red[row][t] += red[row][t + off];
        }
        __syncthreads();
    }
    if (t < 8) {
        tail[t] = red[t][0];
        tail[8 + t] = red[8 + t][0] + be2[t];
    }
    if (t >= 16 && t < 32) tail[t] = 0.f;

    for (int idx = t; idx < 8192; idx += 256) {
        int j = idx & 7, lane = (idx >> 3) & 63, tile = idx >> 9;
        int m = lane & 15, q = lane >> 4;
        int k = q * 8 + j;
        int d = (m >> 2) * 64 + tile * 4 + (m & 3);   // permuted
        float v = 0.f;
        bool lo = false;
        if (k < 5)        v = We1[k * 256 + d];
        else if (k < 10)  { v = We1[(k - 5) * 256 + d]; lo = true; }
        else if (k < 15)  v = We1[(k - 10) * 256 + d];
        else if (k == 15) v = be1[d];
        else if (k == 16) { v = be1[d]; lo = true; }
        ushort hi = f2bf(v);
        W1G[idx] = lo ? f2bf(v - bf2f(hi)) : hi;
    }
    for (int idx = t; idx < 4096; idx += 256) {
        int j = idx & 7, lane = (idx >> 3) & 63, kc = idx >> 9;
        int n = lane & 15, q = lane >> 4;
        int d = kc * 32 + q * 8 + j;
        ushort out;
        if (n < 8)       out = f2bf(g[d] * We2[d * 8 + n]);
        else if (n == 8) out = 0x3F80;   // 1.0 bf16
        else             out = 0;
        B2G[idx] = out;
    }
}

// ---------------------------------------------------------------------------
// gemm_mfma: C[2048,256] = A @ W + bias (fp32-accurate via bf16 hi/lo).
// If Ct != null, write the (per b,h) transposed layout instead (K -> Kt).
// ---------------------------------------------------------------------------
__global__ __launch_bounds__(256) void gemm_mfma(
    const float* __restrict__ A0, const ushort* __restrict__ H0,
    const ushort* __restrict__ L0, const float* __restrict__ b0,
    float* __restrict__ C0, float* __restrict__ T0,
    const float* __restrict__ A1, const ushort* __restrict__ H1,
    const ushort* __restrict__ L1, const float* __restrict__ b1,
    float* __restrict__ C1, float* __restrict__ T1,
    const float* __restrict__ A2, const ushort* __restrict__ H2,
    const ushort* __restrict__ L2, const float* __restrict__ b2,
    float* __restrict__ C2, float* __restrict__ T2)
{
    const float* A; const ushort* BH; const ushort* BL;
    const float* bias; float* C; float* Ct;
    if (blockIdx.z == 0)      { A = A0; BH = H0; BL = L0; bias = b0; C = C0; Ct = T0; }
    else if (blockIdx.z == 1) { A = A1; BH = H1; BL = L1; bias = b1; C = C1; Ct = T1; }
    else                      { A = A2; BH = H2; BL = L2; bias = b2; C = C2; Ct = T2; }

    __shared__ ushort Ahi[64][40];
    __shared__ ushort Alo[64][40];

    int tid = threadIdx.x;
    int wv = tid >> 6, lane = tid & 63;
    int m = lane & 15, quad = lane >> 4;
    int bm = blockIdx.x * 64, bn = blockIdx.y * 64;

    int sm = tid >> 2, sg = (tid & 3) * 8;
    const float* Arow = A + (size_t)(bm + sm) * 256 + sg;

    int nrow = bn + wv * 16 + m;
    const ushort* bhp = BH + (size_t)nrow * 256 + quad * 8;
    const ushort* blp = BL + (size_t)nrow * 256 + quad * 8;

    f32x4 acc[4];
#pragma unroll
    for (int mt = 0; mt < 4; ++mt) acc[mt] = (f32x4){0.f, 0.f, 0.f, 0.f};

    for (int k0 = 0; k0 < 256; k0 += 32) {
        float4 a0 = *(const float4*)(Arow + k0);
        float4 a1 = *(const float4*)(Arow + k0 + 4);
        uint2 c0 = cvt_hilo2(a0.x, a0.y);
        uint2 c1 = cvt_hilo2(a0.z, a0.w);
        uint2 c2 = cvt_hilo2(a1.x, a1.y);
        uint2 c3 = cvt_hilo2(a1.z, a1.w);
        if (k0) __syncthreads();
        uint4 hq; hq.x = c0.x; hq.y = c1.x; hq.z = c2.x; hq.w = c3.x;
        uint4 lq; lq.x = c0.y; lq.y = c1.y; lq.z = c2.y; lq.w = c3.y;
        *(uint4*)&Ahi[sm][sg] = hq;
        *(uint4*)&Alo[sm][sg] = lq;
        __syncthreads();

        short8 bhi = *(const short8*)(bhp + k0);
        short8 blo = *(const short8*)(blp + k0);
#pragma unroll
        for (int mt = 0; mt < 4; ++mt) {
            short8 ahi = *(const short8*)&Ahi[mt * 16 + m][quad * 8];
            short8 alo = *(const short8*)&Alo[mt * 16 + m][quad * 8];
            acc[mt] = __builtin_amdgcn_mfma_f32_16x16x32_bf16(ahi, blo, acc[mt], 0, 0, 0);
            acc[mt] = __builtin_amdgcn_mfma_f32_16x16x32_bf16(alo, bhi, acc[mt], 0, 0, 0);
            acc[mt] = __builtin_amdgcn_mfma_f32_16x16x32_bf16(ahi, bhi, acc[mt], 0, 0, 0);
        }
    }

    float bn_bias = bias[nrow];
    if (Ct) {
        int bb = bm >> 9, l0 = bm & 511;
        float* outp = Ct + ((size_t)(bb * 256 + nrow)) * 512 + l0 + quad * 4;
#pragma unroll
        for (int mt = 0; mt < 4; ++mt) {
            float4 o;
            o.x = acc[mt][0] + bn_bias; o.y = acc[mt][1] + bn_bias;
            o.z = acc[mt][2] + bn_bias; o.w = acc[mt][3] + bn_bias;
            *(float4*)(outp + mt * 16) = o;
        }
    } else {
#pragma unroll
        for (int mt = 0; mt < 4; ++mt) {
#pragma unroll
            for (int r = 0; r < 4; ++r) {
                C[(size_t)(bm + mt * 16 + quad * 4 + r) * 256 + nrow] = acc[mt][r] + bn_bias;
            }
        }
    }
}

// ---------------------------------------------------------------------------
// edge_bias_mfma: r7 version restored exactly (64 us measured) — 2048 blocks
// x 256 thr, single X buffer, EF prefetch-1, single accumulate chains.
// ---------------------------------------------------------------------------
__global__ __launch_bounds__(256) void edge_bias_mfma(
    const float* __restrict__ EF, const ushort* __restrict__ W1G,
    const ushort* __restrict__ B2G, const float* __restrict__ tail,
    ushort* __restrict__ E2)
{
    __shared__ __align__(16) char xt[4 * 16 * 528];  // 33792 B, per-wave tiles
    int tid = threadIdx.x;
    int wv = tid >> 6, lane = tid & 63;
    int q = lane >> 4, n = lane & 15;
    char* myx = xt + wv * (16 * 528);

    int bi = blockIdx.x;            // b*512 + i
    int b = bi >> 9, i = bi & 511;
    size_t rowbase = (size_t)bi * 512;

    short8 w1f[16];
#pragma unroll
    for (int t = 0; t < 16; ++t)
        w1f[t] = *(const short8*)(W1G + (t * 64 + lane) * 8);
    short8 b2f[8];
#pragma unroll
    for (int kc = 0; kc < 8; ++kc)
        b2f[kc] = *(const short8*)(B2G + (kc * 64 + lane) * 8);

    float shv = tail[n];
    float bbv = tail[8 + n];
    const float inv256 = 1.0f / 256.0f;

    const float* efbase = EF + rowbase * 5;
    int pairoff = wv * 16 + n;               // this lane's pair within iter 0

    // prefetch iter 0
    float4 evA = *(const float4*)(efbase + (size_t)pairoff * 5);
    float  evB = efbase[(size_t)pairoff * 5 + 4];

    for (int iter = 0; iter < 8; ++iter) {
        // prefetch next iter's EF while computing this one
        float4 nA; float nB;
        if (iter < 7) {
            const float* p = efbase + (size_t)((iter + 1) * 64 + pairoff) * 5;
            nA = *(const float4*)p;
            nB = p[4];
        }
        int jb = iter * 64 + wv * 16;

        unsigned int hb[5], la[5];
        hb[0] = fbits(evA.x); hb[1] = fbits(evA.y); hb[2] = fbits(evA.z);
        hb[3] = fbits(evA.w); hb[4] = fbits(evB);
        {
            float e0 = evA.x - asf(hb[0] & 0xffff0000u);
            float e1 = evA.y - asf(hb[1] & 0xffff0000u);
            float e2 = evA.z - asf(hb[2] & 0xffff0000u);
            float e3 = evA.w - asf(hb[3] & 0xffff0000u);
            float e4 = evB   - asf(hb[4] & 0xffff0000u);
            la[0] = fbits(e0) + 0x8000u;
            la[1] = fbits(e1) + 0x8000u;
            la[2] = fbits(e2) + 0x8000u;
            la[3] = fbits(e3) + 0x8000u;
            la[4] = fbits(e4) + 0x8000u;
        }
        // q==0 dwords: [h0|h1, h2|h3, h4|h0, h1|h2]; q==1: [h3|h4, l0|l1, l2|l3, l4|ONE]
        unsigned int A0v = packhi(hb[1], hb[0]);
        unsigned int A1v = packhi(hb[3], hb[2]);
        unsigned int A2v = packhi(hb[0], hb[4]);
        unsigned int A3v = packhi(hb[2], hb[1]);
        unsigned int B0v = packhi(hb[4], hb[3]);
        unsigned int B1v = packhi(la[1], la[0]);
        unsigned int B2v = packhi(la[3], la[2]);
        unsigned int B3v = packhi(0x3F800000u, la[4]);
        uint4 efd;
        bool isq0 = (q == 0), isq1 = (q == 1), isq2 = (q == 2);
        efd.x = isq0 ? A0v : isq1 ? B0v : isq2 ? 0x3F80u : 0u;
        efd.y = isq0 ? A1v : isq1 ? B1v : 0u;
        efd.z = isq0 ? A2v : isq1 ? B2v : 0u;
        efd.w = isq0 ? A3v : isq1 ? B3v : 0u;
        short8 ef8;
        __builtin_memcpy(&ef8, &efd, 16);

        // ---- Stage A: X tiles -> LDS (bf16), b128 writes every 2 tiles
        unsigned int pk0 = 0, pk1 = 0;
#pragma unroll
        for (int t = 0; t < 16; ++t) {
            f32x4 z = {0.f, 0.f, 0.f, 0.f};
            f32x4 d1 = __builtin_amdgcn_mfma_f32_16x16x32_bf16(w1f[t], ef8, z, 0, 0, 0);
            float x0 = fmaxf(d1[0], 0.f);
            float x1 = fmaxf(d1[1], 0.f);
            float x2 = fmaxf(d1[2], 0.f);
            float x3 = fmaxf(d1[3], 0.f);
            unsigned int pa = pack_bf16rnd(x0, x1);
            unsigned int pb = pack_bf16rnd(x2, x3);
            if (t & 1) {
                uint4 wq; wq.x = pk0; wq.y = pk1; wq.z = pa; wq.w = pb;
                *(uint4*)(myx + n * 528 + q * 128 + (t - 1) * 8) = wq;
            } else {
                pk0 = pa; pk1 = pb;
            }
        }

        // ---- Stage B: dots+sum via B2, sumsq via X X^T
        f32x4 acc  = {0.f, 0.f, 0.f, 0.f};
        f32x4 acc2 = {0.f, 0.f, 0.f, 0.f};
#pragma unroll
        for (int kc = 0; kc < 8; ++kc) {
            short8 a = *(const short8*)(myx + n * 528 + kc * 64 + q * 16);
            acc  = __builtin_amdgcn_mfma_f32_16x16x32_bf16(a, b2f[kc], acc, 0, 0, 0);
            acc2 = __builtin_amdgcn_mfma_f32_16x16x32_bf16(a, a, acc2, 0, 0, 0);
        }

        // ---- Epilogue: LN fold
        int base = lane & 48;
        float er[4];
#pragma unroll
        for (int r = 0; r < 4; ++r) {
            float sm = __shfl(acc[r], base + 8);
            float sq = __shfl(acc2[r], base + (base >> 2) + r);
            float dot = acc[r];
            float mu = sm * inv256;
            float var = fmaf(-mu, mu, sq * inv256);
            float rs = rsqrtf(var + 1e-5f);
            er[r] = fmaf(dot - mu * shv, rs, bbv);
        }
        if (n < 8) {
            uint2 outv;
            outv.x = pack_bf16rnd(er[0], er[1]);
            outv.y = pack_bf16rnd(er[2], er[3]);
            size_t basep = (((size_t)(b * NH + n) * L_SEQ + i) * L_SEQ) + jb + q * 4;
            *(uint2*)(E2 + basep) = outv;
        }
        evA = nA; evB = nB;
    }
}

// ---------------------------------------------------------------------------
// attn v2: LDS-traffic reduction.
//  - q rows are wave-uniform -> scalar (s_load) reads, qs_t LDS buffer gone.
//  - pbuf stored bf16 in [wave][j][4 rows] layout: softmax writes 4x b128,
//    PV reads one b64 for all 4 rows (was 4x b32).
//  - LDS 51.5 -> 32 KB => 4 blocks/CU (was 3).
// ---------------------------------------------------------------------------
__global__ __launch_bounds__(256, 4) void attn_kernel(
    const float* __restrict__ Q, const float* __restrict__ Kt,
    const float* __restrict__ V, const ushort* __restrict__ E2,
    const int* __restrict__ MSK, float* __restrict__ Y)
{
    __shared__ float stage[4096];         // 16 KB: K chunk [32][128] / V chunk [128][32]
    __shared__ ushort pbuf[4][512][4];    // 16 KB: [wave][j][row] bf16

    int bh = blockIdx.x;
    int b = bh >> 3, h = bh & 7;
    int tid = threadIdx.x;
    int wv = tid >> 6, lane = tid & 63;
    int i0 = blockIdx.y * 16;
    int i = i0 + wv * 4;

    const float* Ktb = Kt + (size_t)bh * (HD * L_SEQ);
    const float* Vb  = V + (size_t)b * L_SEQ * D_EMB + h * HD;

    // wave-uniform scalar pointer to this wave's 4 q rows
    int wvu = __builtin_amdgcn_readfirstlane(wv);
    const float* Qs = Q + ((size_t)(b * L_SEQ + i0 + wvu * 4)) * 256 + h * HD;

    size_t erow = ((size_t)bh * L_SEQ + i) * L_SEQ;
    size_t mrow = ((size_t)b * L_SEQ + i) * L_SEQ;

    // ---- prefetch E2 + mask for all 4 rows x 4 chunks (hidden behind QK^T)
    unsigned int e2p[4][4];
    int2 mkp[4][4];
#pragma unroll
    for (int r = 0; r < 4; ++r)
#pragma unroll
        for (int c = 0; c < 4; ++c) {
            int j = c * 128 + 2 * lane;
            e2p[r][c] = *(const unsigned int*)(E2 + erow + (size_t)r * L_SEQ + j);
            mkp[r][c] = *(const int2*)(MSK + mrow + (size_t)r * L_SEQ + j);
        }

    float s[4][8];
#pragma unroll
    for (int r = 0; r < 4; ++r)
#pragma unroll
        for (int t = 0; t < 8; ++t) s[r][t] = 0.f;

    // ---- phase 1: QK^T over 4 K-chunks
    for (int c = 0; c < 4; ++c) {
        if (c) __syncthreads();
        {
            int d0 = tid >> 5, jj = (tid & 31) * 4;
#pragma unroll
            for (int p = 0; p < 4; ++p) {
                int d = p * 8 + d0;
                float4 kv = *(const float4*)(Ktb + (size_t)d * L_SEQ + c * 128 + jj);
                *(float4*)&stage[d * 128 + jj] = kv;
            }
        }
        __syncthreads();
        int c2 = c * 2;
#pragma unroll
        for (int d = 0; d < HD; ++d) {
            float q0 = Qs[0 * 256 + d];
            float q1 = Qs[1 * 256 + d];
            float q2 = Qs[2 * 256 + d];
            float q3 = Qs[3 * 256 + d];
            float2 kv = *(const float2*)&stage[d * 128 + 2 * lane];
            s[0][c2]     = fmaf(q0, kv.x, s[0][c2]);
            s[0][c2 + 1] = fmaf(q0, kv.y, s[0][c2 + 1]);
            s[1][c2]     = fmaf(q1, kv.x, s[1][c2]);
            s[1][c2 + 1] = fmaf(q1, kv.y, s[1][c2 + 1]);
            s[2][c2]     = fmaf(q2, kv.x, s[2][c2]);
            s[2][c2 + 1] = fmaf(q2, kv.y, s[2][c2 + 1]);
            s[3][c2]     = fmaf(q3, kv.x, s[3][c2]);
            s[3][c2 + 1] = fmaf(q3, kv.y, s[3][c2 + 1]);
        }
    }

    // ---- softmax (p kept in regs across rows, then packed to pbuf bf16)
    const float scl = 0.17677669529663687f;  // 1/sqrt(32)
#pragma unroll
    for (int r = 0; r < 4; ++r) {
        float m = -3.0e38f;
#pragma unroll
        for (int idx = 0; idx < 8; ++idx) {
            int c = idx >> 1, u = idx & 1;
            unsigned int pk = e2p[r][c];
            float e = bf2f((ushort)(u ? (pk >> 16) : (pk & 0xffff)));
            int mk = u ? mkp[r][c].y : mkp[r][c].x;
            float v = (mk != 0) ? fmaf(s[r][idx], scl, e) : -1e30f;
            s[r][idx] = v;
            m = fmaxf(m, v);
        }
#pragma unroll
        for (int o = 32; o > 0; o >>= 1) m = fmaxf(m, __shfl_xor(m, o));
        float ssum = 0.f;
#pragma unroll
        for (int idx = 0; idx < 8; ++idx) {
            float p = __expf(s[r][idx] - m);
            s[r][idx] = p;
            ssum += p;
        }
#pragma unroll
        for (int o = 32; o > 0; o >>= 1) ssum += __shfl_xor(ssum, o);
        float inv = 1.0f / ssum;
#pragma unroll
        for (int idx = 0; idx < 8; ++idx) s[r][idx] *= inv;
    }
    // write p: entry [wv][j][0..3] = rows 0..3 (bf16); j = c*128+2*lane (+1)
#pragma unroll
    for (int c = 0; c < 4; ++c) {
        int c2 = c * 2;
        uint4 w;
        w.x = pack_bf16rnd(s[0][c2],     s[1][c2]);
        w.y = pack_bf16rnd(s[2][c2],     s[3][c2]);
        w.z = pack_bf16rnd(s[0][c2 + 1], s[1][c2 + 1]);
        w.w = pack_bf16rnd(s[2][c2 + 1], s[3][c2 + 1]);
        *(uint4*)&pbuf[wv][c * 128 + 2 * lane][0] = w;
    }

    // ---- phase 2: PV over 4 V-chunks (same stage buffer)
    int dg = lane >> 3, js = lane & 7;
    float4 acc[4];
#pragma unroll
    for (int r = 0; r < 4; ++r) { acc[r].x = 0.f; acc[r].y = 0.f; acc[r].z = 0.f; acc[r].w = 0.f; }

    for (int c = 0; c < 4; ++c) {
        __syncthreads();
        {
            int j0 = tid >> 3, dd = (tid & 7) * 4;
#pragma unroll
            for (int p = 0; p < 4; ++p) {
                int j = p * 32 + j0;
                float4 vv = *(const float4*)(Vb + (size_t)(c * 128 + j) * D_EMB + dd);
                *(float4*)&stage[j * 32 + dd] = vv;
            }
        }
        __syncthreads();
#pragma unroll
        for (int jb = 0; jb < 16; ++jb) {
            int jj = jb * 8 + js;
            float4 v4 = *(const float4*)&stage[jj * 32 + dg * 4];
            uint2 pu = *(const uint2*)&pbuf[wv][c * 128 + jj][0];
            float p0 = asf(pu.x << 16);
            float p1 = asf(pu.x & 0xffff0000u);
            float p2 = asf(pu.y << 16);
            float p3 = asf(pu.y & 0xffff0000u);
            acc[0].x = fmaf(p0, v4.x, acc[0].x);
            acc[0].y = fmaf(p0, v4.y, acc[0].y);
            acc[0].z = fmaf(p0, v4.z, acc[0].z);
            acc[0].w = fmaf(p0, v4.w, acc[0].w);
            acc[1].x = fmaf(p1, v4.x, acc[1].x);
            acc[1].y = fmaf(p1, v4.y, acc[1].y);
            acc[1].z = fmaf(p1, v4.z, acc[1].z);
            acc[1].w = fmaf(p1, v4.w, acc[1].w);
            acc[2].x = fmaf(p2, v4.x, acc[2].x);
            acc[2].y = fmaf(p2, v4.y, acc[2].y);
            acc[2].z = fmaf(p2, v4.z, acc[2].z);
            acc[2].w = fmaf(p2, v4.w, acc[2].w);
            acc[3].x = fmaf(p3, v4.x, acc[3].x);
            acc[3].y = fmaf(p3, v4.y, acc[3].y);
            acc[3].z = fmaf(p3, v4.z, acc[3].z);
            acc[3].w = fmaf(p3, v4.w, acc[3].w);
        }
    }

    // ---- reduce over the 8 j-slots
#pragma unroll
    for (int off = 1; off < 8; off <<= 1) {
#pragma unroll
        for (int r = 0; r < 4; ++r) {
            acc[r].x += __shfl_xor(acc[r].x, off);
            acc[r].y += __shfl_xor(acc[r].y, off);
            acc[r].z += __shfl_xor(acc[r].z, off);
            acc[r].w += __shfl_xor(acc[r].w, off);
        }
    }
    if (js == 0) {
#pragma unroll
        for (int r = 0; r < 4; ++r)
            *(float4*)(Y + ((size_t)(b * L_SEQ + i + r)) * 256 + h * HD + dg * 4) = acc[r];
    }
}

// ---------------------------------------------------------------------------
extern "C" void kernel_launch(void* const* d_in, const int* in_sizes, int n_in,
                              void* d_out, int out_size, void* d_ws, size_t ws_size,
                              hipStream_t stream)
{
    const float* key   = (const float*)d_in[0];
    const float* value = (const float*)d_in[1];
    const float* query = (const float*)d_in[2];
    const int*   msk   = (const int*)d_in[3];
    const float* ef    = (const float*)d_in[4];
    const float* Wk  = (const float*)d_in[5];  const float* bk  = (const float*)d_in[6];
    const float* Wq  = (const float*)d_in[7];  const float* bq  = (const float*)d_in[8];
    const float* Wv  = (const float*)d_in[9];  const float* bv  = (const float*)d_in[10];
    const float* Wp  = (const float*)d_in[11]; const float* bp  = (const float*)d_in[12];
    const float* We1 = (const float*)d_in[13]; const float* be1 = (const float*)d_in[14];
    const float* lng = (const float*)d_in[15]; const float* lnb = (const float*)d_in[16];
    const float* We2 = (const float*)d_in[17]; const float* be2 = (const float*)d_in[18];

    const int MTOK = 4 * L_SEQ;          // 2048 rows
    const int NELT = MTOK * D_EMB;       // 524288

    float* ws    = (float*)d_ws;
    float* Qw    = ws;
    float* Vw    = Qw + NELT;
    float* Yw    = Vw + NELT;
    float* Ktw   = Yw + NELT;
    ushort* W1G  = (ushort*)(Ktw + NELT);   // 8192 bf16
    ushort* B2G  = W1G + 8192;              // 4096 bf16
    float* tail  = (float*)(B2G + 4096);    // 32 floats
    ushort* WThi = (ushort*)(tail + 32);    // 4*65536 bf16 (512 KB)
    ushort* WTlo = WThi + 4 * 65536;        // 4*65536 bf16 (512 KB)
    ushort* E2   = WTlo + 4 * 65536;        // 8388608 bf16 (~16.8 MB)

    hipLaunchKernelGGL(prep_kernel, dim3(65), dim3(256), 0, stream,
                       We1, be1, lng, lnb, We2, be2,
                       Wq, Wk, Wv, Wp,
                       W1G, B2G, tail, WThi, WTlo);
    hipLaunchKernelGGL(gemm_mfma, dim3(32, 4, 3), dim3(256), 0, stream,
                       query, WThi + 0 * 65536, WTlo + 0 * 65536, bq, Qw,  (float*)nullptr,
                       key,   WThi + 1 * 65536, WTlo + 1 * 65536, bk, (float*)nullptr, Ktw,
                       value, WThi + 2 * 65536, WTlo + 2 * 65536, bv, Vw,  (float*)nullptr);
    hipLaunchKernelGGL(edge_bias_mfma, dim3(2048), dim3(256), 0, stream,
                       ef, W1G, B2G, tail, E2);
    hipLaunchKernelGGL(attn_kernel, dim3(32, 32), dim3(256), 0, stream,
                       Qw, Ktw, Vw, E2, msk, Yw);
    hipLaunchKernelGGL(gemm_mfma, dim3(32, 4, 1), dim3(256), 0, stream,
                       Yw, WThi + 3 * 65536, WTlo + 3 * 65536, bp, (float*)d_out, (float*)nullptr,
                       Yw, WThi + 3 * 65536, WTlo + 3 * 65536, bp, (float*)d_out, (float*)nullptr,
                       Yw, WThi + 3 * 65536, WTlo + 3 * 65536, bp, (float*)d_out, (float*)nullptr);
}

// Round 11
// 217.846 us; speedup vs baseline: 1.0917x; 1.0364x over previous
//
#include <hip/hip_runtime.h>
#include <hip/hip_bf16.h>

#define L_SEQ 512
#define D_EMB 256
#define NH 8
#define HD 32
#define LL (L_SEQ * L_SEQ)   // 262144

typedef __attribute__((ext_vector_type(8))) short short8;
typedef __attribute__((ext_vector_type(4))) float f32x4;
typedef unsigned short ushort;

__device__ __forceinline__ float bf2f(ushort u) {
    unsigned int x = ((unsigned int)u) << 16;
    float f;
    __builtin_memcpy(&f, &x, 4);
    return f;
}
__device__ __forceinline__ ushort f2bf(float x) {   // RNE (host-quality), prep only
    __hip_bfloat16 h = __float2bfloat16(x);
    ushort u;
    __builtin_memcpy(&u, &h, 2);
    return u;
}
__device__ __forceinline__ unsigned int fbits(float x) {
    unsigned int u;
    __builtin_memcpy(&u, &x, 4);
    return u;
}
__device__ __forceinline__ float asf(unsigned int u) {
    float f;
    __builtin_memcpy(&f, &u, 4);
    return f;
}
// pack bf16(a) | bf16(b)<<16, nearest-ties-away rounding, 3 VALU ops
__device__ __forceinline__ unsigned int pack_bf16rnd(float a, float b) {
    return __builtin_amdgcn_perm(fbits(b) + 0x8000u, fbits(a) + 0x8000u, 0x07060302u);
}
// hi16(x) | hi16(y)<<16  (one v_perm)
__device__ __forceinline__ unsigned int packhi(unsigned int y, unsigned int x) {
    return __builtin_amdgcn_perm(y, x, 0x07060302u);
}
// hi/lo split of two floats: .x = packed hi pair, .y = packed lo pair
__device__ __forceinline__ uint2 cvt_hilo2(float v0, float v1) {
    unsigned int hi = pack_bf16rnd(v0, v1);
    float h0 = asf(hi << 16);
    float h1 = asf(hi & 0xffff0000u);
    unsigned int lo = pack_bf16rnd(v0 - h0, v1 - h1);
    uint2 r; r.x = hi; r.y = lo;
    return r;
}

// ---------------------------------------------------------------------------
// prep (merged): block 0 builds the edge-kernel tables; blocks 1..64 do the
// projection-weight transpose+hi/lo-split.
// ---------------------------------------------------------------------------
__global__ __launch_bounds__(256) void prep_kernel(
    const float* __restrict__ We1, const float* __restrict__ be1,
    const float* __restrict__ g,   const float* __restrict__ bta,
    const float* __restrict__ We2, const float* __restrict__ be2,
    const float* __restrict__ Wq, const float* __restrict__ Wk,
    const float* __restrict__ Wv, const float* __restrict__ Wp,
    ushort* __restrict__ W1G, ushort* __restrict__ B2G, float* __restrict__ tail,
    ushort* __restrict__ WThi, ushort* __restrict__ WTlo)
{
    int t = threadIdx.x;  // 0..255
    if (blockIdx.x != 0) {
        int bx = blockIdx.x - 1;
        int w = bx >> 4, ny = bx & 15;
        const float* W = (w == 0) ? Wq : (w == 1) ? Wk : (w == 2) ? Wv : Wp;
        ushort* dh = WThi + (size_t)w * 65536;
        ushort* dl = WTlo + (size_t)w * 65536;
        int n = ny * 16 + (t >> 4);
        int k0 = (t & 15) * 16;
        ushort hbuf[16], lbuf[16];
#pragma unroll
        for (int kk = 0; kk < 16; ++kk) {
            float v = W[(size_t)(k0 + kk) * 256 + n];
            unsigned int hb = fbits(v) + 0x8000u;
            ushort hi = (ushort)(hb >> 16);
            float res = v - bf2f(hi);
            hbuf[kk] = hi;
            lbuf[kk] = (ushort)((fbits(res) + 0x8000u) >> 16);
        }
        *(short8*)(dh + (size_t)n * 256 + k0)     = *(short8*)&hbuf[0];
        *(short8*)(dh + (size_t)n * 256 + k0 + 8) = *(short8*)&hbuf[8];
        *(short8*)(dl + (size_t)n * 256 + k0)     = *(short8*)&lbuf[0];
        *(short8*)(dl + (size_t)n * 256 + k0 + 8) = *(short8*)&lbuf[8];
        return;
    }

    __shared__ float red[16][256];
    float gd = g[t], bd = bta[t];
#pragma unroll
    for (int h = 0; h < 8; ++h) {
        float w2 = We2[t * 8 + h];
        red[h][t] = gd * w2;
        red[8 + h][t] = bd * w2;
    }
    __syncthreads();
    for (int off = 128; off > 0; off >>= 1) {
        if (t < off) {
#pragma unroll
            for (int row = 0; row < 16; ++row) red[row][t] += red[row][t + off];
        }
        __syncthreads();
    }
    if (t < 8) {
        tail[t] = red[t][0];
        tail[8 + t] = red[8 + t][0] + be2[t];
    }
    if (t >= 16 && t < 32) tail[t] = 0.f;

    for (int idx = t; idx < 8192; idx += 256) {
        int j = idx & 7, lane = (idx >> 3) & 63, tile = idx >> 9;
        int m = lane & 15, q = lane >> 4;
        int k = q * 8 + j;
        int d = (m >> 2) * 64 + tile * 4 + (m & 3);   // permuted
        float v = 0.f;
        bool lo = false;
        if (k < 5)        v = We1[k * 256 + d];
        else if (k < 10)  { v = We1[(k - 5) * 256 + d]; lo = true; }
        else if (k < 15)  v = We1[(k - 10) * 256 + d];
        else if (k == 15) v = be1[d];
        else if (k == 16) { v = be1[d]; lo = true; }
        ushort hi = f2bf(v);
        W1G[idx] = lo ? f2bf(v - bf2f(hi)) : hi;
    }
    for (int idx = t; idx < 4096; idx += 256) {
        int j = idx & 7, lane = (idx >> 3) & 63, kc = idx >> 9;
        int n = lane & 15, q = lane >> 4;
        int d = kc * 32 + q * 8 + j;
        ushort out;
        if (n < 8)       out = f2bf(g[d] * We2[d * 8 + n]);
        else if (n == 8) out = 0x3F80;   // 1.0 bf16
        else             out = 0;
        B2G[idx] = out;
    }
}

// ---------------------------------------------------------------------------
// gemm body: C[2048,256] = A @ W + bias (fp32-accurate via bf16 hi/lo).
// If Ct != null, write the (per b,h) transposed Kt layout instead.
// smem needs 10240 B: Ahi[64][40] | Alo[64][40].
// ---------------------------------------------------------------------------
__device__ __forceinline__ void gemm_body(
    const float* __restrict__ A, const ushort* __restrict__ BH,
    const ushort* __restrict__ BL, const float* __restrict__ bias,
    float* __restrict__ C, float* __restrict__ Ct,
    int bx, int by, char* smem)
{
    ushort* Ahi = (ushort*)smem;            // [64][40]
    ushort* Alo = (ushort*)(smem + 5120);   // [64][40]

    int tid = threadIdx.x;
    int wv = tid >> 6, lane = tid & 63;
    int m = lane & 15, quad = lane >> 4;
    int bm = bx * 64, bn = by * 64;

    int sm = tid >> 2, sg = (tid & 3) * 8;
    const float* Arow = A + (size_t)(bm + sm) * 256 + sg;

    int nrow = bn + wv * 16 + m;
    const ushort* bhp = BH + (size_t)nrow * 256 + quad * 8;
    const ushort* blp = BL + (size_t)nrow * 256 + quad * 8;

    f32x4 acc[4];
#pragma unroll
    for (int mt = 0; mt < 4; ++mt) acc[mt] = (f32x4){0.f, 0.f, 0.f, 0.f};

    for (int k0 = 0; k0 < 256; k0 += 32) {
        float4 a0 = *(const float4*)(Arow + k0);
        float4 a1 = *(const float4*)(Arow + k0 + 4);
        uint2 c0 = cvt_hilo2(a0.x, a0.y);
        uint2 c1 = cvt_hilo2(a0.z, a0.w);
        uint2 c2 = cvt_hilo2(a1.x, a1.y);
        uint2 c3 = cvt_hilo2(a1.z, a1.w);
        if (k0) __syncthreads();
        uint4 hq; hq.x = c0.x; hq.y = c1.x; hq.z = c2.x; hq.w = c3.x;
        uint4 lq; lq.x = c0.y; lq.y = c1.y; lq.z = c2.y; lq.w = c3.y;
        *(uint4*)&Ahi[sm * 40 + sg] = hq;
        *(uint4*)&Alo[sm * 40 + sg] = lq;
        __syncthreads();

        short8 bhi = *(const short8*)(bhp + k0);
        short8 blo = *(const short8*)(blp + k0);
#pragma unroll
        for (int mt = 0; mt < 4; ++mt) {
            short8 ahi = *(const short8*)&Ahi[(mt * 16 + m) * 40 + quad * 8];
            short8 alo = *(const short8*)&Alo[(mt * 16 + m) * 40 + quad * 8];
            acc[mt] = __builtin_amdgcn_mfma_f32_16x16x32_bf16(ahi, blo, acc[mt], 0, 0, 0);
            acc[mt] = __builtin_amdgcn_mfma_f32_16x16x32_bf16(alo, bhi, acc[mt], 0, 0, 0);
            acc[mt] = __builtin_amdgcn_mfma_f32_16x16x32_bf16(ahi, bhi, acc[mt], 0, 0, 0);
        }
    }

    float bn_bias = bias[nrow];
    if (Ct) {
        int bb = bm >> 9, l0 = bm & 511;
        float* outp = Ct + ((size_t)(bb * 256 + nrow)) * 512 + l0 + quad * 4;
#pragma unroll
        for (int mt = 0; mt < 4; ++mt) {
            float4 o;
            o.x = acc[mt][0] + bn_bias; o.y = acc[mt][1] + bn_bias;
            o.z = acc[mt][2] + bn_bias; o.w = acc[mt][3] + bn_bias;
            *(float4*)(outp + mt * 16) = o;
        }
    } else {
#pragma unroll
        for (int mt = 0; mt < 4; ++mt) {
#pragma unroll
            for (int r = 0; r < 4; ++r) {
                C[(size_t)(bm + mt * 16 + quad * 4 + r) * 256 + nrow] = acc[mt][r] + bn_bias;
            }
        }
    }
}

// ---------------------------------------------------------------------------
// edge body: r7 structure exactly (single X buffer, EF prefetch-1).
// smem needs 33792 B (4 waves x 16 x 528).
// ---------------------------------------------------------------------------
__device__ __forceinline__ void edge_body(
    const float* __restrict__ EF, const ushort* __restrict__ W1G,
    const ushort* __restrict__ B2G, const float* __restrict__ tail,
    ushort* __restrict__ E2, int bi, char* smem)
{
    int tid = threadIdx.x;
    int wv = tid >> 6, lane = tid & 63;
    int q = lane >> 4, n = lane & 15;
    char* myx = smem + wv * (16 * 528);

    int b = bi >> 9, i = bi & 511;
    size_t rowbase = (size_t)bi * 512;

    short8 w1f[16];
#pragma unroll
    for (int t = 0; t < 16; ++t)
        w1f[t] = *(const short8*)(W1G + (t * 64 + lane) * 8);
    short8 b2f[8];
#pragma unroll
    for (int kc = 0; kc < 8; ++kc)
        b2f[kc] = *(const short8*)(B2G + (kc * 64 + lane) * 8);

    float shv = tail[n];
    float bbv = tail[8 + n];
    const float inv256 = 1.0f / 256.0f;

    const float* efbase = EF + rowbase * 5;
    int pairoff = wv * 16 + n;

    float4 evA = *(const float4*)(efbase + (size_t)pairoff * 5);
    float  evB = efbase[(size_t)pairoff * 5 + 4];

    for (int iter = 0; iter < 8; ++iter) {
        float4 nA; float nB;
        if (iter < 7) {
            const float* p = efbase + (size_t)((iter + 1) * 64 + pairoff) * 5;
            nA = *(const float4*)p;
            nB = p[4];
        }
        int jb = iter * 64 + wv * 16;

        unsigned int hb[5], la[5];
        hb[0] = fbits(evA.x); hb[1] = fbits(evA.y); hb[2] = fbits(evA.z);
        hb[3] = fbits(evA.w); hb[4] = fbits(evB);
        {
            float e0 = evA.x - asf(hb[0] & 0xffff0000u);
            float e1 = evA.y - asf(hb[1] & 0xffff0000u);
            float e2 = evA.z - asf(hb[2] & 0xffff0000u);
            float e3 = evA.w - asf(hb[3] & 0xffff0000u);
            float e4 = evB   - asf(hb[4] & 0xffff0000u);
            la[0] = fbits(e0) + 0x8000u;
            la[1] = fbits(e1) + 0x8000u;
            la[2] = fbits(e2) + 0x8000u;
            la[3] = fbits(e3) + 0x8000u;
            la[4] = fbits(e4) + 0x8000u;
        }
        unsigned int A0v = packhi(hb[1], hb[0]);
        unsigned int A1v = packhi(hb[3], hb[2]);
        unsigned int A2v = packhi(hb[0], hb[4]);
        unsigned int A3v = packhi(hb[2], hb[1]);
        unsigned int B0v = packhi(hb[4], hb[3]);
        unsigned int B1v = packhi(la[1], la[0]);
        unsigned int B2v = packhi(la[3], la[2]);
        unsigned int B3v = packhi(0x3F800000u, la[4]);
        uint4 efd;
        bool isq0 = (q == 0), isq1 = (q == 1), isq2 = (q == 2);
        efd.x = isq0 ? A0v : isq1 ? B0v : isq2 ? 0x3F80u : 0u;
        efd.y = isq0 ? A1v : isq1 ? B1v : 0u;
        efd.z = isq0 ? A2v : isq1 ? B2v : 0u;
        efd.w = isq0 ? A3v : isq1 ? B3v : 0u;
        short8 ef8;
        __builtin_memcpy(&ef8, &efd, 16);

        unsigned int pk0 = 0, pk1 = 0;
#pragma unroll
        for (int t = 0; t < 16; ++t) {
            f32x4 z = {0.f, 0.f, 0.f, 0.f};
            f32x4 d1 = __builtin_amdgcn_mfma_f32_16x16x32_bf16(w1f[t], ef8, z, 0, 0, 0);
            float x0 = fmaxf(d1[0], 0.f);
            float x1 = fmaxf(d1[1], 0.f);
            float x2 = fmaxf(d1[2], 0.f);
            float x3 = fmaxf(d1[3], 0.f);
            unsigned int pa = pack_bf16rnd(x0, x1);
            unsigned int pb = pack_bf16rnd(x2, x3);
            if (t & 1) {
                uint4 wq; wq.x = pk0; wq.y = pk1; wq.z = pa; wq.w = pb;
                *(uint4*)(myx + n * 528 + q * 128 + (t - 1) * 8) = wq;
            } else {
                pk0 = pa; pk1 = pb;
            }
        }

        f32x4 acc  = {0.f, 0.f, 0.f, 0.f};
        f32x4 acc2 = {0.f, 0.f, 0.f, 0.f};
#pragma unroll
        for (int kc = 0; kc < 8; ++kc) {
            short8 a = *(const short8*)(myx + n * 528 + kc * 64 + q * 16);
            acc  = __builtin_amdgcn_mfma_f32_16x16x32_bf16(a, b2f[kc], acc, 0, 0, 0);
            acc2 = __builtin_amdgcn_mfma_f32_16x16x32_bf16(a, a, acc2, 0, 0, 0);
        }

        int base = lane & 48;
        float er[4];
#pragma unroll
        for (int r = 0; r < 4; ++r) {
            float sm = __shfl(acc[r], base + 8);
            float sq = __shfl(acc2[r], base + (base >> 2) + r);
            float dot = acc[r];
            float mu = sm * inv256;
            float var = fmaf(-mu, mu, sq * inv256);
            float rs = rsqrtf(var + 1e-5f);
            er[r] = fmaf(dot - mu * shv, rs, bbv);
        }
        if (n < 8) {
            uint2 outv;
            outv.x = pack_bf16rnd(er[0], er[1]);
            outv.y = pack_bf16rnd(er[2], er[3]);
            size_t basep = (((size_t)(b * NH + n) * L_SEQ + i) * L_SEQ) + jb + q * 4;
            *(uint2*)(E2 + basep) = outv;
        }
        evA = nA; evB = nB;
    }
}

// ---------------------------------------------------------------------------
// fused_qkv_edge: blocks 0..383 = QKV gemms (independent MFMA-heavy work),
// blocks 384..2431 = edge rows (latency-bound). Co-scheduling overlaps the
// two (m114: MFMA and VALU waves on one CU run concurrently).
// ---------------------------------------------------------------------------
__global__ __launch_bounds__(256) void fused_qkv_edge(
    const float* __restrict__ query, const float* __restrict__ key,
    const float* __restrict__ value,
    const ushort* __restrict__ WThi, const ushort* __restrict__ WTlo,
    const float* __restrict__ bq, const float* __restrict__ bk,
    const float* __restrict__ bv,
    float* __restrict__ Qw, float* __restrict__ Ktw, float* __restrict__ Vw,
    const float* __restrict__ EF, const ushort* __restrict__ W1G,
    const ushort* __restrict__ B2G, const float* __restrict__ tail,
    ushort* __restrict__ E2)
{
    __shared__ __align__(16) char smem[4 * 16 * 528];  // 33792 B (union)
    int bid = blockIdx.x;
    if (bid < 384) {
        int z = bid >> 7, rem = bid & 127;
        int bx = rem & 31, by = rem >> 5;
        if (z == 0)
            gemm_body(query, WThi + 0 * 65536, WTlo + 0 * 65536, bq, Qw, nullptr, bx, by, smem);
        else if (z == 1)
            gemm_body(key,   WThi + 1 * 65536, WTlo + 1 * 65536, bk, nullptr, Ktw, bx, by, smem);
        else
            gemm_body(value, WThi + 2 * 65536, WTlo + 2 * 65536, bv, Vw, nullptr, bx, by, smem);
    } else {
        edge_body(EF, W1G, B2G, tail, E2, bid - 384, smem);
    }
}

// ---------------------------------------------------------------------------
// gemm_out: output projection only (single problem).
// ---------------------------------------------------------------------------
__global__ __launch_bounds__(256) void gemm_out(
    const float* __restrict__ A, const ushort* __restrict__ BH,
    const ushort* __restrict__ BL, const float* __restrict__ bias,
    float* __restrict__ C)
{
    __shared__ __align__(16) char smem[10240];
    gemm_body(A, BH, BL, bias, C, nullptr, blockIdx.x, blockIdx.y, smem);
}

// ---------------------------------------------------------------------------
// attn v2 (round 10, unchanged): scalar q loads, bf16 pbuf.
// ---------------------------------------------------------------------------
__global__ __launch_bounds__(256, 4) void attn_kernel(
    const float* __restrict__ Q, const float* __restrict__ Kt,
    const float* __restrict__ V, const ushort* __restrict__ E2,
    const int* __restrict__ MSK, float* __restrict__ Y)
{
    __shared__ float stage[4096];         // 16 KB: K chunk [32][128] / V chunk [128][32]
    __shared__ ushort pbuf[4][512][4];    // 16 KB: [wave][j][row] bf16

    int bh = blockIdx.x;
    int b = bh >> 3, h = bh & 7;
    int tid = threadIdx.x;
    int wv = tid >> 6, lane = tid & 63;
    int i0 = blockIdx.y * 16;
    int i = i0 + wv * 4;

    const float* Ktb = Kt + (size_t)bh * (HD * L_SEQ);
    const float* Vb  = V + (size_t)b * L_SEQ * D_EMB + h * HD;

    int wvu = __builtin_amdgcn_readfirstlane(wv);
    const float* Qs = Q + ((size_t)(b * L_SEQ + i0 + wvu * 4)) * 256 + h * HD;

    size_t erow = ((size_t)bh * L_SEQ + i) * L_SEQ;
    size_t mrow = ((size_t)b * L_SEQ + i) * L_SEQ;

    unsigned int e2p[4][4];
    int2 mkp[4][4];
#pragma unroll
    for (int r = 0; r < 4; ++r)
#pragma unroll
        for (int c = 0; c < 4; ++c) {
            int j = c * 128 + 2 * lane;
            e2p[r][c] = *(const unsigned int*)(E2 + erow + (size_t)r * L_SEQ + j);
            mkp[r][c] = *(const int2*)(MSK + mrow + (size_t)r * L_SEQ + j);
        }

    float s[4][8];
#pragma unroll
    for (int r = 0; r < 4; ++r)
#pragma unroll
        for (int t = 0; t < 8; ++t) s[r][t] = 0.f;

    for (int c = 0; c < 4; ++c) {
        if (c) __syncthreads();
        {
            int d0 = tid >> 5, jj = (tid & 31) * 4;
#pragma unroll
            for (int p = 0; p < 4; ++p) {
                int d = p * 8 + d0;
                float4 kv = *(const float4*)(Ktb + (size_t)d * L_SEQ + c * 128 + jj);
                *(float4*)&stage[d * 128 + jj] = kv;
            }
        }
        __syncthreads();
        int c2 = c * 2;
#pragma unroll
        for (int d = 0; d < HD; ++d) {
            float q0 = Qs[0 * 256 + d];
            float q1 = Qs[1 * 256 + d];
            float q2 = Qs[2 * 256 + d];
            float q3 = Qs[3 * 256 + d];
            float2 kv = *(const float2*)&stage[d * 128 + 2 * lane];
            s[0][c2]     = fmaf(q0, kv.x, s[0][c2]);
            s[0][c2 + 1] = fmaf(q0, kv.y, s[0][c2 + 1]);
            s[1][c2]     = fmaf(q1, kv.x, s[1][c2]);
            s[1][c2 + 1] = fmaf(q1, kv.y, s[1][c2 + 1]);
            s[2][c2]     = fmaf(q2, kv.x, s[2][c2]);
            s[2][c2 + 1] = fmaf(q2, kv.y, s[2][c2 + 1]);
            s[3][c2]     = fmaf(q3, kv.x, s[3][c2]);
            s[3][c2 + 1] = fmaf(q3, kv.y, s[3][c2 + 1]);
        }
    }

    const float scl = 0.17677669529663687f;  // 1/sqrt(32)
#pragma unroll
    for (int r = 0; r < 4; ++r) {
        float m = -3.0e38f;
#pragma unroll
        for (int idx = 0; idx < 8; ++idx) {
            int c = idx >> 1, u = idx & 1;
            unsigned int pk = e2p[r][c];
            float e = bf2f((ushort)(u ? (pk >> 16) : (pk & 0xffff)));
            int mk = u ? mkp[r][c].y : mkp[r][c].x;
            float v = (mk != 0) ? fmaf(s[r][idx], scl, e) : -1e30f;
            s[r][idx] = v;
            m = fmaxf(m, v);
        }
#pragma unroll
        for (int o = 32; o > 0; o >>= 1) m = fmaxf(m, __shfl_xor(m, o));
        float ssum = 0.f;
#pragma unroll
        for (int idx = 0; idx < 8; ++idx) {
            float p = __expf(s[r][idx] - m);
            s[r][idx] = p;
            ssum += p;
        }
#pragma unroll
        for (int o = 32; o > 0; o >>= 1) ssum += __shfl_xor(ssum, o);
        float inv = 1.0f / ssum;
#pragma unroll
        for (int idx = 0; idx < 8; ++idx) s[r][idx] *= inv;
    }
#pragma unroll
    for (int c = 0; c < 4; ++c) {
        int c2 = c * 2;
        uint4 w;
        w.x = pack_bf16rnd(s[0][c2],     s[1][c2]);
        w.y = pack_bf16rnd(s[2][c2],     s[3][c2]);
        w.z = pack_bf16rnd(s[0][c2 + 1], s[1][c2 + 1]);
        w.w = pack_bf16rnd(s[2][c2 + 1], s[3][c2 + 1]);
        *(uint4*)&pbuf[wv][c * 128 + 2 * lane][0] = w;
    }

    int dg = lane >> 3, js = lane & 7;
    float4 acc[4];
#pragma unroll
    for (int r = 0; r < 4; ++r) { acc[r].x = 0.f; acc[r].y = 0.f; acc[r].z = 0.f; acc[r].w = 0.f; }

    for (int c = 0; c < 4; ++c) {
        __syncthreads();
        {
            int j0 = tid >> 3, dd = (tid & 7) * 4;
#pragma unroll
            for (int p = 0; p < 4; ++p) {
                int j = p * 32 + j0;
                float4 vv = *(const float4*)(Vb + (size_t)(c * 128 + j) * D_EMB + dd);
                *(float4*)&stage[j * 32 + dd] = vv;
            }
        }
        __syncthreads();
#pragma unroll
        for (int jb = 0; jb < 16; ++jb) {
            int jj = jb * 8 + js;
            float4 v4 = *(const float4*)&stage[jj * 32 + dg * 4];
            uint2 pu = *(const uint2*)&pbuf[wv][c * 128 + jj][0];
            float p0 = asf(pu.x << 16);
            float p1 = asf(pu.x & 0xffff0000u);
            float p2 = asf(pu.y << 16);
            float p3 = asf(pu.y & 0xffff0000u);
            acc[0].x = fmaf(p0, v4.x, acc[0].x);
            acc[0].y = fmaf(p0, v4.y, acc[0].y);
            acc[0].z = fmaf(p0, v4.z, acc[0].z);
            acc[0].w = fmaf(p0, v4.w, acc[0].w);
            acc[1].x = fmaf(p1, v4.x, acc[1].x);
            acc[1].y = fmaf(p1, v4.y, acc[1].y);
            acc[1].z = fmaf(p1, v4.z, acc[1].z);
            acc[1].w = fmaf(p1, v4.w, acc[1].w);
            acc[2].x = fmaf(p2, v4.x, acc[2].x);
            acc[2].y = fmaf(p2, v4.y, acc[2].y);
            acc[2].z = fmaf(p2, v4.z, acc[2].z);
            acc[2].w = fmaf(p2, v4.w, acc[2].w);
            acc[3].x = fmaf(p3, v4.x, acc[3].x);
            acc[3].y = fmaf(p3, v4.y, acc[3].y);
            acc[3].z = fmaf(p3, v4.z, acc[3].z);
            acc[3].w = fmaf(p3, v4.w, acc[3].w);
        }
    }

#pragma unroll
    for (int off = 1; off < 8; off <<= 1) {
#pragma unroll
        for (int r = 0; r < 4; ++r) {
            acc[r].x += __shfl_xor(acc[r].x, off);
            acc[r].y += __shfl_xor(acc[r].y, off);
            acc[r].z += __shfl_xor(acc[r].z, off);
            acc[r].w += __shfl_xor(acc[r].w, off);
        }
    }
    if (js == 0) {
#pragma unroll
        for (int r = 0; r < 4; ++r)
            *(float4*)(Y + ((size_t)(b * L_SEQ + i + r)) * 256 + h * HD + dg * 4) = acc[r];
    }
}

// ---------------------------------------------------------------------------
extern "C" void kernel_launch(void* const* d_in, const int* in_sizes, int n_in,
                              void* d_out, int out_size, void* d_ws, size_t ws_size,
                              hipStream_t stream)
{
    const float* key   = (const float*)d_in[0];
    const float* value = (const float*)d_in[1];
    const float* query = (const float*)d_in[2];
    const int*   msk   = (const int*)d_in[3];
    const float* ef    = (const float*)d_in[4];
    const float* Wk  = (const float*)d_in[5];  const float* bk  = (const float*)d_in[6];
    const float* Wq  = (const float*)d_in[7];  const float* bq  = (const float*)d_in[8];
    const float* Wv  = (const float*)d_in[9];  const float* bv  = (const float*)d_in[10];
    const float* Wp  = (const float*)d_in[11]; const float* bp  = (const float*)d_in[12];
    const float* We1 = (const float*)d_in[13]; const float* be1 = (const float*)d_in[14];
    const float* lng = (const float*)d_in[15]; const float* lnb = (const float*)d_in[16];
    const float* We2 = (const float*)d_in[17]; const float* be2 = (const float*)d_in[18];

    const int MTOK = 4 * L_SEQ;          // 2048 rows
    const int NELT = MTOK * D_EMB;       // 524288

    float* ws    = (float*)d_ws;
    float* Qw    = ws;
    float* Vw    = Qw + NELT;
    float* Yw    = Vw + NELT;
    float* Ktw   = Yw + NELT;
    ushort* W1G  = (ushort*)(Ktw + NELT);   // 8192 bf16
    ushort* B2G  = W1G + 8192;              // 4096 bf16
    float* tail  = (float*)(B2G + 4096);    // 32 floats
    ushort* WThi = (ushort*)(tail + 32);    // 4*65536 bf16 (512 KB)
    ushort* WTlo = WThi + 4 * 65536;        // 4*65536 bf16 (512 KB)
    ushort* E2   = WTlo + 4 * 65536;        // 8388608 bf16 (~16.8 MB)

    hipLaunchKernelGGL(prep_kernel, dim3(65), dim3(256), 0, stream,
                       We1, be1, lng, lnb, We2, be2,
                       Wq, Wk, Wv, Wp,
                       W1G, B2G, tail, WThi, WTlo);
    hipLaunchKernelGGL(fused_qkv_edge, dim3(2432), dim3(256), 0, stream,
                       query, key, value, WThi, WTlo, bq, bk, bv,
                       Qw, Ktw, Vw,
                       ef, W1G, B2G, tail, E2);
    hipLaunchKernelGGL(attn_kernel, dim3(32, 32), dim3(256), 0, stream,
                       Qw, Ktw, Vw, E2, msk, Yw);
    hipLaunchKernelGGL(gemm_out, dim3(32, 4), dim3(256), 0, stream,
                       Yw, WThi + 3 * 65536, WTlo + 3 * 65536, bp, (float*)d_out);
}